// Round 5
// baseline (322.575 us; speedup 1.0000x reference)
//
#include <hip/hip_runtime.h>
#include <math.h>

typedef __attribute__((ext_vector_type(8))) short b8;
typedef __attribute__((ext_vector_type(4))) short s4;
typedef __attribute__((ext_vector_type(4))) float f4;
typedef float f4u __attribute__((ext_vector_type(4), aligned(4)));  // align-4 float4

// ws layout (float-element offsets)
#define WS_OFFS   0                 // 294912 (B*18*HW)
#define WS_GY0    294912            // float4[147456] = 589824 floats
#define WS_GY1    884736            // float4[147456]
#define WS_IP     1474560           // int2[147456]  = 294912 floats
#define WS_AFRAG  1769472           // bf16[589824]  = 294912 floats
#define WS_BFOLD  2064384           // 256
// total 2064640 floats = 8,258,560 bytes (same as R1 budget, known OK)

__device__ inline ushort f2bf(float f) {
  uint u = __float_as_uint(f);
  return (ushort)((u + 0x7FFFu + ((u >> 16) & 1u)) >> 16);   // RNE
}

// ---------------------------------------------------------------------------
// prep: pack A-fragments (weight*BN, bf16) in iteration order.
// iter i in [0,72): cg=i/9 (32-ch group), kk=i%9.
// afrag[((i*16+ot)*64+l)*8+j] = w[o][c][kk]*inv[o],
//   o = ot*16 + (l&15),  c = cg*32 + (l>>4)*8 + j
// ---------------------------------------------------------------------------
__global__ __launch_bounds__(256) void prep_k(
    const float* __restrict__ w, const float* __restrict__ bias,
    const float* __restrict__ gamma, const float* __restrict__ beta,
    const float* __restrict__ mean, const float* __restrict__ var,
    float* __restrict__ ws) {
  const int tid = blockIdx.x * 256 + threadIdx.x;    // < 73728
  const int l  = tid & 63;
  const int ot = (tid >> 6) & 15;
  const int i  = tid >> 10;          // 0..71
  const int cg = i / 9;
  const int kk = i - cg * 9;
  const int o  = (ot << 4) + (l & 15);
  const int cb = (cg << 5) + ((l >> 4) << 3);
  const float inv = gamma[o] * rsqrtf(var[o] + 1e-5f);
  b8 pk;
#pragma unroll
  for (int j = 0; j < 8; ++j)
    pk[j] = (short)f2bf(w[((o << 8) + cb + j) * 9 + kk] * inv);
  *(b8*)((short*)(ws + WS_AFRAG) + tid * 8) = pk;
  if (tid < 256) {
    const float iv = gamma[tid] * rsqrtf(var[tid] + 1e-5f);
    ws[WS_BFOLD + tid] = bias[tid] * iv + beta[tid] - mean[tid] * iv;
  }
}

// ---------------------------------------------------------------------------
// K1: offset conv. grid 256 = (b<<6)|ho. 4 waves; wave wv covers ch
// [wv*64, wv*64+64). Row loads coalesced, neighbors via shfl, weight
// addresses wave-uniform -> s_loads. LDS reduce -> final store (no atomics).
// ---------------------------------------------------------------------------
__global__ __launch_bounds__(256) void offset_conv_k(
    const float* __restrict__ x, const float* __restrict__ wof,
    float* __restrict__ ws) {
  __shared__ float red[4][18][64];
  const int bid = blockIdx.x;
  const int b   = bid >> 6;
  const int ho  = bid & 63;
  const int t   = threadIdx.x;
  const int wo  = t & 63;
  const int wv  = __builtin_amdgcn_readfirstlane(t >> 6);

  float acc[18];
#pragma unroll
  for (int i = 0; i < 18; ++i) acc[i] = 0.f;

  const float vl = (wo >= 1) ? 1.f : 0.f;
  const float vr = (wo <= 62) ? 1.f : 0.f;
  const int yc0 = max(ho - 1, 0), yc2 = min(ho + 1, 63);
  const float vy0 = (ho >= 1) ? 1.f : 0.f;
  const float vy2 = (ho <= 62) ? 1.f : 0.f;
  const int cbase = wv << 6;
  const float* xb = x + ((long)b << 20) + ((long)cbase << 12);

  for (int c = 0; c < 64; ++c) {
    const float* xp = xb + (c << 12);
    float m0 = xp[(yc0 << 6) + wo] * vy0;
    float m1 = xp[(ho << 6) + wo];
    float m2 = xp[(yc2 << 6) + wo] * vy2;
    float v[9];
    v[0] = __shfl_up(m0, 1) * vl;  v[1] = m0;  v[2] = __shfl_down(m0, 1) * vr;
    v[3] = __shfl_up(m1, 1) * vl;  v[4] = m1;  v[5] = __shfl_down(m1, 1) * vr;
    v[6] = __shfl_up(m2, 1) * vl;  v[7] = m2;  v[8] = __shfl_down(m2, 1) * vr;
    const int cc = cbase + c;      // uniform
#pragma unroll
    for (int oc = 0; oc < 18; ++oc) {
      const float* wp = wof + ((oc << 8) + cc) * 9;   // uniform -> s_load
#pragma unroll
      for (int kk = 0; kk < 9; ++kk) acc[oc] = fmaf(wp[kk], v[kk], acc[oc]);
    }
  }
#pragma unroll
  for (int oc = 0; oc < 18; ++oc) red[wv][oc][wo] = acc[oc];
  __syncthreads();
  for (int i = t; i < 18 * 64; i += 256) {
    const int oc = i >> 6, w2 = i & 63;
    ws[WS_OFFS + ((b * 18 + oc) << 12) + (ho << 6) + w2] =
        red[0][oc][w2] + red[1][oc][w2] + red[2][oc][w2] + red[3][oc][w2];
  }
}

// ---------------------------------------------------------------------------
// K2: quad descriptors. Per (k,n): even base col xf=min(x0c&~1,60), 8 weights
// gy0[0..3] (row y0c, cols xf..xf+3) and gy1[0..3] (row y1c), plus
// p0=(y0c<<6)+xf, p1=(y1c<<6)+xf. Sample = dot(gy0, x[p0..p0+3]) + dot(gy1,..)
// ---------------------------------------------------------------------------
__global__ __launch_bounds__(256) void make_desc_k(
    const float* __restrict__ bof, float* __restrict__ ws) {
  const int d  = blockIdx.x * 256 + threadIdx.x;    // < 147456
  const int k  = d >> 14;
  const int n  = d & 16383;
  const int b  = n >> 12;
  const int sp = n & 4095;
  const int ho = sp >> 6, wo = sp & 63;
  const int ky = k / 3, kx = k - ky * 3;
  const float dy = ws[WS_OFFS + ((b * 18 + (k << 1)) << 12) + sp] + bof[k << 1];
  const float dx = ws[WS_OFFS + ((b * 18 + (k << 1) + 1) << 12) + sp] + bof[(k << 1) + 1];
  const float py = (float)(ho - 1 + ky) + dy;
  const float px = (float)(wo - 1 + kx) + dx;
  const float y0f = floorf(py), x0f = floorf(px);
  const float ly = py - y0f, lx = px - x0f;
  const int y0 = (int)y0f, x0 = (int)x0f;
  const int y1 = y0 + 1, x1 = x0 + 1;
  const float vy0 = (y0 >= 0 && y0 < 64) ? 1.f : 0.f;
  const float vy1 = (y1 >= 0 && y1 < 64) ? 1.f : 0.f;
  const float vx0 = (x0 >= 0 && x0 < 64) ? 1.f : 0.f;
  const float vx1 = (x1 >= 0 && x1 < 64) ? 1.f : 0.f;
  const int y0c = min(max(y0, 0), 63), y1c = min(max(y1, 0), 63);
  const int x0c = min(max(x0, 0), 63), x1c = min(max(x1, 0), 63);
  const float w00 = (1.f - ly) * (1.f - lx) * vy0 * vx0;
  const float w01 = (1.f - ly) * lx * vy0 * vx1;
  const float w10 = ly * (1.f - lx) * vy1 * vx0;
  const float w11 = ly * lx * vy1 * vx1;
  const int xf = min(x0c & ~1, 60);
  f4 g0 = {0.f, 0.f, 0.f, 0.f}, g1 = {0.f, 0.f, 0.f, 0.f};
#pragma unroll
  for (int j = 0; j < 4; ++j) {
    const int col = xf + j;
    g0[j] = (col == x0c ? w00 : 0.f) + (col == x1c ? w01 : 0.f);
    g1[j] = (col == x0c ? w10 : 0.f) + (col == x1c ? w11 : 0.f);
  }
  ((f4*)(ws + WS_GY0))[d] = g0;
  ((f4*)(ws + WS_GY1))[d] = g1;
  int2 ip; ip.x = (y0c << 6) + xf; ip.y = (y1c << 6) + xf;
  ((int2*)(ws + WS_IP))[d] = ip;
}

// ---------------------------------------------------------------------------
// K3: bf16 MFMA GEMM, fused deformable im2col, quad-descriptor gathers.
// Grid 512: xcd=bid&7, batch=xcd>>1, j=bid>>3;
//   row = ((xcd&1)<<5)+(j&31), nhalf=j>>5; sp0 = row*64 + nhalf*32.
// Block tile 256(o) x 32(n), 4 waves of 64o x 32n, BK=32 (c in group),
// cg-outer/kk-inner. Descs for 9k x 32cols cached in LDS. Dbuf B LDS.
// Each B sample gathered exactly once device-wide (no o-split redundancy).
// ---------------------------------------------------------------------------
__global__ __launch_bounds__(256, 2) void deform_gemm_k(
    const float* __restrict__ x, const float* __restrict__ ws,
    float* __restrict__ out) {
  __shared__ ushort Bs[2][32][40];
  __shared__ f4   dG0[288];
  __shared__ f4   dG1[288];
  __shared__ int2 dIP[288];

  const int t     = threadIdx.x;
  const int bid   = blockIdx.x;
  const int xcd   = bid & 7;
  const int batch = xcd >> 1;
  const int j     = bid >> 3;                    // 0..63
  const int row   = ((xcd & 1) << 5) + (j & 31);
  const int sp0   = (row << 6) + ((j >> 5) << 5);
  const int nd0   = (batch << 12) + sp0;
  const int l     = t & 63;
  const int wv    = t >> 6;

  const int sn = t & 31;              // sample column 0..31
  const int cs = t >> 5;              // 4-ch slice 0..7
  const float* xb = x + ((long)batch << 20);
  const short* af = (const short*)(ws + WS_AFRAG);

  // ---- fill descriptor LDS (288 = 9k x 32 cols) ----
  for (int u = t; u < 288; u += 256) {
    const int kk = u >> 5, s = u & 31;
    const int dg = (kk << 14) + nd0 + s;
    dG0[u] = ((const f4*)(ws + WS_GY0))[dg];
    dG1[u] = ((const f4*)(ws + WS_GY1))[dg];
    dIP[u] = ((const int2*)(ws + WS_IP))[dg];
  }
  __syncthreads();

  f4 acc[4][2];
#pragma unroll
  for (int i = 0; i < 4; ++i)
#pragma unroll
    for (int q = 0; q < 2; ++q) acc[i][q] = f4{0.f, 0.f, 0.f, 0.f};

  const int otb = wv << 2;            // wave's first o-tile
  b8 aA[4], aN[4];
  f4 g0, g1; int p0, p1;              // descriptor for pending gather
  f4u r0[4], r1[4];                   // gathered quads, 4 channels

#define RDDESC(KK_) do { const int u_ = ((KK_) << 5) + sn;                   \
    g0 = dG0[u_]; g1 = dG1[u_];                                              \
    const int2 ip_ = dIP[u_]; p0 = ip_.x; p1 = ip_.y; } while (0)

#define GATHER(CG_) do {                                                     \
    const int c0_ = ((CG_) << 5) + (cs << 2);                                \
    _Pragma("unroll")                                                        \
    for (int q = 0; q < 4; ++q) {                                            \
      const float* pl_ = xb + ((c0_ + q) << 12);                             \
      r0[q] = *(const f4u*)(pl_ + p0);                                       \
      r1[q] = *(const f4u*)(pl_ + p1);                                       \
    } } while (0)

#define COMBINE(BUF_) do {                                                   \
    s4 pk_;                                                                  \
    _Pragma("unroll")                                                        \
    for (int q = 0; q < 4; ++q) {                                            \
      float v_ = g0.x * r0[q].x + g0.y * r0[q].y + g0.z * r0[q].z +          \
                 g0.w * r0[q].w + g1.x * r1[q].x + g1.y * r1[q].y +          \
                 g1.z * r1[q].z + g1.w * r1[q].w;                            \
      pk_[q] = (short)f2bf(v_);                                              \
    }                                                                        \
    *(s4*)&Bs[BUF_][sn][cs << 2] = pk_; } while (0)

#define LOADA(I_, DST_) do {                                                 \
    _Pragma("unroll")                                                        \
    for (int m = 0; m < 4; ++m)                                              \
      DST_[m] = *(const b8*)(af + (((((I_) << 4) + otb + m) << 6) + l) * 8); \
  } while (0)

  // prologue: iter 0 = (cg0, kk0)
  RDDESC(0);
  GATHER(0);
  LOADA(0, aA);
  COMBINE(0);
  RDDESC(1);                          // desc for iter 1
  __syncthreads();

  int kkN = 1, cgN = 0;               // (kk, cg) of iter i+1
  for (int i = 0; i < 72; ++i) {
    const int cur = i & 1;
    if (i < 71) {
      GATHER(cgN);                    // gather for iter i+1 (desc in g/p)
      LOADA(i + 1, aN);
    }
    b8 bB[2];
#pragma unroll
    for (int nt = 0; nt < 2; ++nt)
      bB[nt] = *(const b8*)&Bs[cur][(nt << 4) + (l & 15)][(l >> 4) << 3];
#pragma unroll
    for (int mt = 0; mt < 4; ++mt)
#pragma unroll
      for (int nt = 0; nt < 2; ++nt)
        acc[mt][nt] = __builtin_amdgcn_mfma_f32_16x16x32_bf16(
            aA[mt], bB[nt], acc[mt][nt], 0, 0, 0);
    if (i < 71) {
      COMBINE(cur ^ 1);
      kkN++; if (kkN == 9) { kkN = 0; cgN++; }
      if (i < 70) RDDESC(kkN);
#pragma unroll
      for (int m = 0; m < 4; ++m) aA[m] = aN[m];
    }
    __syncthreads();
  }

  const float* bfold = ws + WS_BFOLD;
  const int q4 = (l >> 4) << 2;
  const int ow = wv << 6;
#pragma unroll
  for (int mt = 0; mt < 4; ++mt) {
    const int ob = ow + (mt << 4) + q4;
    const f4 bf = *(const f4*)&bfold[ob];
#pragma unroll
    for (int nt = 0; nt < 2; ++nt) {
      const int sp = sp0 + (nt << 4) + (l & 15);
#pragma unroll
      for (int r = 0; r < 4; ++r) {
        const int o = ob + r;
        out[(((batch << 8) + o) << 12) + sp] =
            fmaxf(acc[mt][nt][r] + bf[r], 0.f);
      }
    }
  }
}

// ---------------------------------------------------------------------------
extern "C" void kernel_launch(void* const* d_in, const int* in_sizes, int n_in,
                              void* d_out, int out_size, void* d_ws, size_t ws_size,
                              hipStream_t stream) {
  const float* x     = (const float*)d_in[0];
  const float* wof   = (const float*)d_in[1];
  const float* bof   = (const float*)d_in[2];
  const float* w     = (const float*)d_in[3];
  const float* bias  = (const float*)d_in[4];
  const float* gamma = (const float*)d_in[5];
  const float* beta  = (const float*)d_in[6];
  const float* mean  = (const float*)d_in[7];
  const float* var   = (const float*)d_in[8];
  float* out = (float*)d_out;
  float* ws  = (float*)d_ws;

  hipLaunchKernelGGL(prep_k, dim3(288), dim3(256), 0, stream,
                     w, bias, gamma, beta, mean, var, ws);
  hipLaunchKernelGGL(offset_conv_k, dim3(256), dim3(256), 0, stream,
                     x, wof, ws);
  hipLaunchKernelGGL(make_desc_k, dim3(576), dim3(256), 0, stream,
                     bof, ws);
  hipLaunchKernelGGL(deform_gemm_k, dim3(512), dim3(256), 0, stream,
                     x, ws, out);
}

// Round 6
// 218.254 us; speedup vs baseline: 1.4780x; 1.4780x over previous
//
#include <hip/hip_runtime.h>
#include <math.h>

typedef __attribute__((ext_vector_type(8))) short b8;
typedef __attribute__((ext_vector_type(4))) short s4;
typedef __attribute__((ext_vector_type(4))) float f4;
typedef float f4u __attribute__((ext_vector_type(4), aligned(4)));  // align-4 float4

// ws layout (float-element offsets)
#define WS_OFFS   0                 // 294912 (B*18*HW)
#define WS_GY0    294912            // float4[147456] = 589824 floats
#define WS_GY1    884736            // float4[147456]
#define WS_IP     1474560           // int2[147456]  = 294912 floats
#define WS_AFRAG  1769472           // bf16[589824]  = 294912 floats
#define WS_BFOLD  2064384           // 256
// K1 offset-conv weight frags live INSIDE the GY0 region: written by prep,
// read by K1, then overwritten by K2 (which runs after K1). No ws growth.
#define WS_K1WH   294912            // bf16[73728] = 36864 floats
#define WS_K1WL   331776            // bf16[73728]
// total 2064640 floats = 8,258,560 bytes

__device__ inline ushort f2bf(float f) {
  uint u = __float_as_uint(f);
  return (ushort)((u + 0x7FFFu + ((u >> 16) & 1u)) >> 16);   // RNE
}

// ---------------------------------------------------------------------------
// prep: (a) main-GEMM A-frags (weight*BN, bf16) in iteration order;
// (b) folded bias; (c) K1 offset-conv A-frags, bf16 SPLIT (wh + wl), M
// padded 18->32, same (cg,kk) iteration order, layout ((i*2+mt)*64+l)*8+j.
// ---------------------------------------------------------------------------
__global__ __launch_bounds__(256) void prep_k(
    const float* __restrict__ w, const float* __restrict__ wof,
    const float* __restrict__ bias,
    const float* __restrict__ gamma, const float* __restrict__ beta,
    const float* __restrict__ mean, const float* __restrict__ var,
    float* __restrict__ ws) {
  const int tid = blockIdx.x * 256 + threadIdx.x;    // < 73728
  const int l  = tid & 63;
  const int ot = (tid >> 6) & 15;
  const int i  = tid >> 10;          // 0..71
  const int cg = i / 9;
  const int kk = i - cg * 9;
  const int o  = (ot << 4) + (l & 15);
  const int cb = (cg << 5) + ((l >> 4) << 3);
  const float inv = gamma[o] * rsqrtf(var[o] + 1e-5f);
  b8 pk;
#pragma unroll
  for (int j = 0; j < 8; ++j)
    pk[j] = (short)f2bf(w[((o << 8) + cb + j) * 9 + kk] * inv);
  *(b8*)((short*)(ws + WS_AFRAG) + tid * 8) = pk;
  if (tid < 256) {
    const float iv = gamma[tid] * rsqrtf(var[tid] + 1e-5f);
    ws[WS_BFOLD + tid] = bias[tid] * iv + beta[tid] - mean[tid] * iv;
  }
  // (c) K1 offset-conv weight frags, split precision
  if (tid < 9216) {
    const int l2  = tid & 63;
    const int mt  = (tid >> 6) & 1;
    const int i2  = tid >> 7;        // 0..71
    const int cg2 = i2 / 9;
    const int kk2 = i2 - cg2 * 9;
    const int oc  = (mt << 4) + (l2 & 15);
    const int cb2 = (cg2 << 5) + ((l2 >> 4) << 3);
    b8 ph, pl;
#pragma unroll
    for (int j = 0; j < 8; ++j) {
      const float v = (oc < 18) ? wof[((oc << 8) + cb2 + j) * 9 + kk2] : 0.f;
      const ushort h = f2bf(v);
      const float hf = __uint_as_float((uint)h << 16);
      ph[j] = (short)h;
      pl[j] = (short)f2bf(v - hf);
    }
    *(b8*)((short*)(ws + WS_K1WH) + tid * 8) = ph;
    *(b8*)((short*)(ws + WS_K1WL) + tid * 8) = pl;
  }
}

// ---------------------------------------------------------------------------
// K1: offset conv as bf16-split MFMA GEMM. Grid 256 = (b<<6)|ho.
// Block: out tile 32(oc; 18 real) x 64(wo), K=2304 as 8 cgs x (32c x 9kk).
// Per cg: stage x rows ho-1..ho+1, 32 ch, into bordered LDS tile
// [3][66][40] (c innermost, zero borders for pad), bf16 high+low.
// Per kk: B-frag = one ds_read_b128 per operand (2-way banks = free);
// acc = xh*wh + xh*wl + xl*wh (fp32 acc) -> ~fp24-accurate offsets.
// ---------------------------------------------------------------------------
__global__ __launch_bounds__(256) void offset_mfma_k(
    const float* __restrict__ x, float* __restrict__ ws) {
  __shared__ __align__(16) ushort Xh[3][66][40];
  __shared__ __align__(16) ushort Xl[3][66][40];
  const int bid = blockIdx.x;
  const int b   = bid >> 6;
  const int ho  = bid & 63;
  const int t   = threadIdx.x;
  const int l   = t & 63;
  const int wv  = t >> 6;
  const short* afh = (const short*)(ws + WS_K1WH);
  const short* afl = (const short*)(ws + WS_K1WL);

  // zero col borders (LDS col index 0 and 65), all rows, all 40 c-slots
  for (int u = t; u < 240; u += 256) {
    const int row = u / 80, rem = u % 80;
    const int col = (rem >= 40) ? 65 : 0;
    const int c   = rem % 40;
    Xh[row][col][c] = 0;
    Xl[row][col][c] = 0;
  }

  f4 acc[2];
  acc[0] = f4{0.f, 0.f, 0.f, 0.f};
  acc[1] = f4{0.f, 0.f, 0.f, 0.f};

  const int cidx = t >> 3;           // channel within group 0..31
  const int j8   = t & 7;
  const float* xc = x + ((long)b << 20) + ((long)cidx << 12);
  const int col = (wv << 4) + (l & 15);
  const int qc  = (l >> 4) << 3;     // c-offset of this lane's frag

  for (int cg = 0; cg < 8; ++cg) {
    __syncthreads();                 // LDS safe to rewrite (also covers init)
    const float* xg = xc + ((long)(cg << 5) << 12);
#pragma unroll
    for (int rep = 0; rep < 6; ++rep) {
      const int fi   = (rep << 3) + j8;    // 0..47
      const int row  = fi >> 4;            // 0..2
      const int colf = (fi & 15) << 2;     // 0..60
      const int y = ho - 1 + row;
      f4u v = {0.f, 0.f, 0.f, 0.f};
      if (y >= 0 && y <= 63) v = *(const f4u*)(xg + (y << 6) + colf);
#pragma unroll
      for (int q = 0; q < 4; ++q) {
        const ushort h = f2bf(v[q]);
        const float hf = __uint_as_float((uint)h << 16);
        Xh[row][colf + 1 + q][cidx] = h;
        Xl[row][colf + 1 + q][cidx] = f2bf(v[q] - hf);
      }
    }
    __syncthreads();
#pragma unroll
    for (int kk = 0; kk < 9; ++kk) {
      const int ky = kk / 3, kx = kk - ky * 3;   // consts after unroll
      const int i  = cg * 9 + kk;
      const b8 ah0 = *(const b8*)(afh + ((((i << 1) + 0) << 6) + l) * 8);
      const b8 ah1 = *(const b8*)(afh + ((((i << 1) + 1) << 6) + l) * 8);
      const b8 al0 = *(const b8*)(afl + ((((i << 1) + 0) << 6) + l) * 8);
      const b8 al1 = *(const b8*)(afl + ((((i << 1) + 1) << 6) + l) * 8);
      const b8 bh = *(const b8*)&Xh[ky][col + kx][qc];
      const b8 bl = *(const b8*)&Xl[ky][col + kx][qc];
      acc[0] = __builtin_amdgcn_mfma_f32_16x16x32_bf16(ah0, bh, acc[0], 0, 0, 0);
      acc[0] = __builtin_amdgcn_mfma_f32_16x16x32_bf16(ah0, bl, acc[0], 0, 0, 0);
      acc[0] = __builtin_amdgcn_mfma_f32_16x16x32_bf16(al0, bh, acc[0], 0, 0, 0);
      acc[1] = __builtin_amdgcn_mfma_f32_16x16x32_bf16(ah1, bh, acc[1], 0, 0, 0);
      acc[1] = __builtin_amdgcn_mfma_f32_16x16x32_bf16(ah1, bl, acc[1], 0, 0, 0);
      acc[1] = __builtin_amdgcn_mfma_f32_16x16x32_bf16(al1, bh, acc[1], 0, 0, 0);
    }
  }

  // store oc<18 (C layout: col=lane&15, row=(lane>>4)*4+reg)
  const int wo = col;
  const int q4 = (l >> 4) << 2;
#pragma unroll
  for (int mt = 0; mt < 2; ++mt)
#pragma unroll
    for (int r = 0; r < 4; ++r) {
      const int oc = (mt << 4) + q4 + r;
      if (oc < 18)
        ws[WS_OFFS + ((b * 18 + oc) << 12) + (ho << 6) + wo] = acc[mt][r];
    }
}

// ---------------------------------------------------------------------------
// K2: quad descriptors. Per (k,n): even base col xf=min(x0c&~1,60), 8 weights
// gy0[0..3] (row y0c, cols xf..xf+3) and gy1[0..3] (row y1c), plus
// p0=(y0c<<6)+xf, p1=(y1c<<6)+xf. Sample = dot(gy0, x[p0..p0+3]) + dot(gy1,..)
// ---------------------------------------------------------------------------
__global__ __launch_bounds__(256) void make_desc_k(
    const float* __restrict__ bof, float* __restrict__ ws) {
  const int d  = blockIdx.x * 256 + threadIdx.x;    // < 147456
  const int k  = d >> 14;
  const int n  = d & 16383;
  const int b  = n >> 12;
  const int sp = n & 4095;
  const int ho = sp >> 6, wo = sp & 63;
  const int ky = k / 3, kx = k - ky * 3;
  const float dy = ws[WS_OFFS + ((b * 18 + (k << 1)) << 12) + sp] + bof[k << 1];
  const float dx = ws[WS_OFFS + ((b * 18 + (k << 1) + 1) << 12) + sp] + bof[(k << 1) + 1];
  const float py = (float)(ho - 1 + ky) + dy;
  const float px = (float)(wo - 1 + kx) + dx;
  const float y0f = floorf(py), x0f = floorf(px);
  const float ly = py - y0f, lx = px - x0f;
  const int y0 = (int)y0f, x0 = (int)x0f;
  const int y1 = y0 + 1, x1 = x0 + 1;
  const float vy0 = (y0 >= 0 && y0 < 64) ? 1.f : 0.f;
  const float vy1 = (y1 >= 0 && y1 < 64) ? 1.f : 0.f;
  const float vx0 = (x0 >= 0 && x0 < 64) ? 1.f : 0.f;
  const float vx1 = (x1 >= 0 && x1 < 64) ? 1.f : 0.f;
  const int y0c = min(max(y0, 0), 63), y1c = min(max(y1, 0), 63);
  const int x0c = min(max(x0, 0), 63), x1c = min(max(x1, 0), 63);
  const float w00 = (1.f - ly) * (1.f - lx) * vy0 * vx0;
  const float w01 = (1.f - ly) * lx * vy0 * vx1;
  const float w10 = ly * (1.f - lx) * vy1 * vx0;
  const float w11 = ly * lx * vy1 * vx1;
  const int xf = min(x0c & ~1, 60);
  f4 g0 = {0.f, 0.f, 0.f, 0.f}, g1 = {0.f, 0.f, 0.f, 0.f};
#pragma unroll
  for (int j = 0; j < 4; ++j) {
    const int col = xf + j;
    g0[j] = (col == x0c ? w00 : 0.f) + (col == x1c ? w01 : 0.f);
    g1[j] = (col == x0c ? w10 : 0.f) + (col == x1c ? w11 : 0.f);
  }
  ((f4*)(ws + WS_GY0))[d] = g0;
  ((f4*)(ws + WS_GY1))[d] = g1;
  int2 ip; ip.x = (y0c << 6) + xf; ip.y = (y1c << 6) + xf;
  ((int2*)(ws + WS_IP))[d] = ip;
}

// ---------------------------------------------------------------------------
// K3: bf16 MFMA GEMM, fused deformable im2col, quad-descriptor gathers.
// Grid 512: xcd=bid&7, batch=xcd>>1, j=bid>>3;
//   row = ((xcd&1)<<5)+(j&31), nhalf=j>>5; sp0 = row*64 + nhalf*32.
// Block tile 256(o) x 32(n), 4 waves of 64o x 32n, BK=32 (c in group),
// cg-outer/kk-inner. Descs for 9k x 32cols cached in LDS. Dbuf B LDS.
// Each B sample gathered exactly once device-wide (no o-split redundancy).
// ---------------------------------------------------------------------------
__global__ __launch_bounds__(256, 2) void deform_gemm_k(
    const float* __restrict__ x, const float* __restrict__ ws,
    float* __restrict__ out) {
  __shared__ ushort Bs[2][32][40];
  __shared__ f4   dG0[288];
  __shared__ f4   dG1[288];
  __shared__ int2 dIP[288];

  const int t     = threadIdx.x;
  const int bid   = blockIdx.x;
  const int xcd   = bid & 7;
  const int batch = xcd >> 1;
  const int j     = bid >> 3;                    // 0..63
  const int row   = ((xcd & 1) << 5) + (j & 31);
  const int sp0   = (row << 6) + ((j >> 5) << 5);
  const int nd0   = (batch << 12) + sp0;
  const int l     = t & 63;
  const int wv    = t >> 6;

  const int sn = t & 31;              // sample column 0..31
  const int cs = t >> 5;              // 4-ch slice 0..7
  const float* xb = x + ((long)batch << 20);
  const short* af = (const short*)(ws + WS_AFRAG);

  // ---- fill descriptor LDS (288 = 9k x 32 cols) ----
  for (int u = t; u < 288; u += 256) {
    const int kk = u >> 5, s = u & 31;
    const int dg = (kk << 14) + nd0 + s;
    dG0[u] = ((const f4*)(ws + WS_GY0))[dg];
    dG1[u] = ((const f4*)(ws + WS_GY1))[dg];
    dIP[u] = ((const int2*)(ws + WS_IP))[dg];
  }
  __syncthreads();

  f4 acc[4][2];
#pragma unroll
  for (int i = 0; i < 4; ++i)
#pragma unroll
    for (int q = 0; q < 2; ++q) acc[i][q] = f4{0.f, 0.f, 0.f, 0.f};

  const int otb = wv << 2;            // wave's first o-tile
  b8 aA[4], aN[4];
  f4 g0, g1; int p0, p1;              // descriptor for pending gather
  f4u r0[4], r1[4];                   // gathered quads, 4 channels

#define RDDESC(KK_) do { const int u_ = ((KK_) << 5) + sn;                   \
    g0 = dG0[u_]; g1 = dG1[u_];                                              \
    const int2 ip_ = dIP[u_]; p0 = ip_.x; p1 = ip_.y; } while (0)

#define GATHER(CG_) do {                                                     \
    const int c0_ = ((CG_) << 5) + (cs << 2);                                \
    _Pragma("unroll")                                                        \
    for (int q = 0; q < 4; ++q) {                                            \
      const float* pl_ = xb + ((c0_ + q) << 12);                             \
      r0[q] = *(const f4u*)(pl_ + p0);                                       \
      r1[q] = *(const f4u*)(pl_ + p1);                                       \
    } } while (0)

#define COMBINE(BUF_) do {                                                   \
    s4 pk_;                                                                  \
    _Pragma("unroll")                                                        \
    for (int q = 0; q < 4; ++q) {                                            \
      float v_ = g0.x * r0[q].x + g0.y * r0[q].y + g0.z * r0[q].z +          \
                 g0.w * r0[q].w + g1.x * r1[q].x + g1.y * r1[q].y +          \
                 g1.z * r1[q].z + g1.w * r1[q].w;                            \
      pk_[q] = (short)f2bf(v_);                                              \
    }                                                                        \
    *(s4*)&Bs[BUF_][sn][cs << 2] = pk_; } while (0)

#define LOADA(I_, DST_) do {                                                 \
    _Pragma("unroll")                                                        \
    for (int m = 0; m < 4; ++m)                                              \
      DST_[m] = *(const b8*)(af + (((((I_) << 4) + otb + m) << 6) + l) * 8); \
  } while (0)

  // prologue: iter 0 = (cg0, kk0)
  RDDESC(0);
  GATHER(0);
  LOADA(0, aA);
  COMBINE(0);
  RDDESC(1);                          // desc for iter 1
  __syncthreads();

  int kkN = 1, cgN = 0;               // (kk, cg) of iter i+1
  for (int i = 0; i < 72; ++i) {
    const int cur = i & 1;
    if (i < 71) {
      GATHER(cgN);                    // gather for iter i+1 (desc in g/p)
      LOADA(i + 1, aN);
    }
    b8 bB[2];
#pragma unroll
    for (int nt = 0; nt < 2; ++nt)
      bB[nt] = *(const b8*)&Bs[cur][(nt << 4) + (l & 15)][(l >> 4) << 3];
#pragma unroll
    for (int mt = 0; mt < 4; ++mt)
#pragma unroll
      for (int nt = 0; nt < 2; ++nt)
        acc[mt][nt] = __builtin_amdgcn_mfma_f32_16x16x32_bf16(
            aA[mt], bB[nt], acc[mt][nt], 0, 0, 0);
    if (i < 71) {
      COMBINE(cur ^ 1);
      kkN++; if (kkN == 9) { kkN = 0; cgN++; }
      if (i < 70) RDDESC(kkN);
#pragma unroll
      for (int m = 0; m < 4; ++m) aA[m] = aN[m];
    }
    __syncthreads();
  }

  const float* bfold = ws + WS_BFOLD;
  const int q4 = (l >> 4) << 2;
  const int ow = wv << 6;
#pragma unroll
  for (int mt = 0; mt < 4; ++mt) {
    const int ob = ow + (mt << 4) + q4;
    const f4 bf = *(const f4*)&bfold[ob];
#pragma unroll
    for (int nt = 0; nt < 2; ++nt) {
      const int sp = sp0 + (nt << 4) + (l & 15);
#pragma unroll
      for (int r = 0; r < 4; ++r) {
        const int o = ob + r;
        out[(((batch << 8) + o) << 12) + sp] =
            fmaxf(acc[mt][nt][r] + bf[r], 0.f);
      }
    }
  }
}

// ---------------------------------------------------------------------------
extern "C" void kernel_launch(void* const* d_in, const int* in_sizes, int n_in,
                              void* d_out, int out_size, void* d_ws, size_t ws_size,
                              hipStream_t stream) {
  const float* x     = (const float*)d_in[0];
  const float* wof   = (const float*)d_in[1];
  const float* bof   = (const float*)d_in[2];
  const float* w     = (const float*)d_in[3];
  const float* bias  = (const float*)d_in[4];
  const float* gamma = (const float*)d_in[5];
  const float* beta  = (const float*)d_in[6];
  const float* mean  = (const float*)d_in[7];
  const float* var   = (const float*)d_in[8];
  float* out = (float*)d_out;
  float* ws  = (float*)d_ws;

  hipLaunchKernelGGL(prep_k, dim3(288), dim3(256), 0, stream,
                     w, wof, bias, gamma, beta, mean, var, ws);
  hipLaunchKernelGGL(offset_mfma_k, dim3(256), dim3(256), 0, stream,
                     x, ws);
  hipLaunchKernelGGL(make_desc_k, dim3(576), dim3(256), 0, stream,
                     bof, ws);
  hipLaunchKernelGGL(deform_gemm_k, dim3(512), dim3(256), 0, stream,
                     x, ws, out);
}

// Round 7
// 216.756 us; speedup vs baseline: 1.4882x; 1.0069x over previous
//
#include <hip/hip_runtime.h>
#include <math.h>

typedef __attribute__((ext_vector_type(8))) short b8;
typedef __attribute__((ext_vector_type(4))) short s4;
typedef __attribute__((ext_vector_type(4))) float f4;
typedef float f4u __attribute__((ext_vector_type(4), aligned(4)));  // align-4 float4

// ws layout (float-element offsets)
#define WS_OFFS   0                 // 294912 (B*18*HW)
#define WS_GY0    294912            // float4[147456] = 589824 floats
#define WS_GY1    884736            // float4[147456]
#define WS_IP     1474560           // int2[147456]  = 294912 floats
#define WS_AFRAG  1769472           // bf16[589824]  = 294912 floats
#define WS_BFOLD  2064384           // 256
// K1 offset-conv weight frags live INSIDE the GY0 region: written by prep,
// read by K1, then overwritten by K2 (which runs after K1). No ws growth.
#define WS_K1WH   294912            // bf16[73728] = 36864 floats
#define WS_K1WL   331776            // bf16[73728]
// total 2064640 floats = 8,258,560 bytes

__device__ inline ushort f2bf(float f) {
  uint u = __float_as_uint(f);
  return (ushort)((u + 0x7FFFu + ((u >> 16) & 1u)) >> 16);   // RNE
}

// ---------------------------------------------------------------------------
// prep: (a) main-GEMM A-frags (weight*BN, bf16) in iteration order;
// (b) folded bias; (c) K1 offset-conv A-frags, bf16 SPLIT (wh + wl), M
// padded 18->32, same (cg,kk) iteration order, layout ((i*2+mt)*64+l)*8+j.
// ---------------------------------------------------------------------------
__global__ __launch_bounds__(256) void prep_k(
    const float* __restrict__ w, const float* __restrict__ wof,
    const float* __restrict__ bias,
    const float* __restrict__ gamma, const float* __restrict__ beta,
    const float* __restrict__ mean, const float* __restrict__ var,
    float* __restrict__ ws) {
  const int tid = blockIdx.x * 256 + threadIdx.x;    // < 73728
  const int l  = tid & 63;
  const int ot = (tid >> 6) & 15;
  const int i  = tid >> 10;          // 0..71
  const int cg = i / 9;
  const int kk = i - cg * 9;
  const int o  = (ot << 4) + (l & 15);
  const int cb = (cg << 5) + ((l >> 4) << 3);
  const float inv = gamma[o] * rsqrtf(var[o] + 1e-5f);
  b8 pk;
#pragma unroll
  for (int j = 0; j < 8; ++j)
    pk[j] = (short)f2bf(w[((o << 8) + cb + j) * 9 + kk] * inv);
  *(b8*)((short*)(ws + WS_AFRAG) + tid * 8) = pk;
  if (tid < 256) {
    const float iv = gamma[tid] * rsqrtf(var[tid] + 1e-5f);
    ws[WS_BFOLD + tid] = bias[tid] * iv + beta[tid] - mean[tid] * iv;
  }
  // (c) K1 offset-conv weight frags, split precision
  if (tid < 9216) {
    const int l2  = tid & 63;
    const int mt  = (tid >> 6) & 1;
    const int i2  = tid >> 7;        // 0..71
    const int cg2 = i2 / 9;
    const int kk2 = i2 - cg2 * 9;
    const int oc  = (mt << 4) + (l2 & 15);
    const int cb2 = (cg2 << 5) + ((l2 >> 4) << 3);
    b8 ph, pl;
#pragma unroll
    for (int j = 0; j < 8; ++j) {
      const float v = (oc < 18) ? wof[((oc << 8) + cb2 + j) * 9 + kk2] : 0.f;
      const ushort h = f2bf(v);
      const float hf = __uint_as_float((uint)h << 16);
      ph[j] = (short)h;
      pl[j] = (short)f2bf(v - hf);
    }
    *(b8*)((short*)(ws + WS_K1WH) + tid * 8) = ph;
    *(b8*)((short*)(ws + WS_K1WL) + tid * 8) = pl;
  }
}

// ---------------------------------------------------------------------------
// K1: offset conv as bf16-split MFMA GEMM. Grid 256 = (b<<6)|ho.
// ---------------------------------------------------------------------------
__global__ __launch_bounds__(256) void offset_mfma_k(
    const float* __restrict__ x, float* __restrict__ ws) {
  __shared__ __align__(16) ushort Xh[3][66][40];
  __shared__ __align__(16) ushort Xl[3][66][40];
  const int bid = blockIdx.x;
  const int b   = bid >> 6;
  const int ho  = bid & 63;
  const int t   = threadIdx.x;
  const int l   = t & 63;
  const int wv  = t >> 6;
  const short* afh = (const short*)(ws + WS_K1WH);
  const short* afl = (const short*)(ws + WS_K1WL);

  // zero col borders (LDS col index 0 and 65), all rows, all 40 c-slots
  for (int u = t; u < 240; u += 256) {
    const int row = u / 80, rem = u % 80;
    const int col = (rem >= 40) ? 65 : 0;
    const int c   = rem % 40;
    Xh[row][col][c] = 0;
    Xl[row][col][c] = 0;
  }

  f4 acc[2];
  acc[0] = f4{0.f, 0.f, 0.f, 0.f};
  acc[1] = f4{0.f, 0.f, 0.f, 0.f};

  const int cidx = t >> 3;           // channel within group 0..31
  const int j8   = t & 7;
  const float* xc = x + ((long)b << 20) + ((long)cidx << 12);
  const int col = (wv << 4) + (l & 15);
  const int qc  = (l >> 4) << 3;     // c-offset of this lane's frag

  for (int cg = 0; cg < 8; ++cg) {
    __syncthreads();                 // LDS safe to rewrite (also covers init)
    const float* xg = xc + ((long)(cg << 5) << 12);
#pragma unroll
    for (int rep = 0; rep < 6; ++rep) {
      const int fi   = (rep << 3) + j8;    // 0..47
      const int row  = fi >> 4;            // 0..2
      const int colf = (fi & 15) << 2;     // 0..60
      const int y = ho - 1 + row;
      f4u v = {0.f, 0.f, 0.f, 0.f};
      if (y >= 0 && y <= 63) v = *(const f4u*)(xg + (y << 6) + colf);
#pragma unroll
      for (int q = 0; q < 4; ++q) {
        const ushort h = f2bf(v[q]);
        const float hf = __uint_as_float((uint)h << 16);
        Xh[row][colf + 1 + q][cidx] = h;
        Xl[row][colf + 1 + q][cidx] = f2bf(v[q] - hf);
      }
    }
    __syncthreads();
#pragma unroll
    for (int kk = 0; kk < 9; ++kk) {
      const int ky = kk / 3, kx = kk - ky * 3;   // consts after unroll
      const int i  = cg * 9 + kk;
      const b8 ah0 = *(const b8*)(afh + ((((i << 1) + 0) << 6) + l) * 8);
      const b8 ah1 = *(const b8*)(afh + ((((i << 1) + 1) << 6) + l) * 8);
      const b8 al0 = *(const b8*)(afl + ((((i << 1) + 0) << 6) + l) * 8);
      const b8 al1 = *(const b8*)(afl + ((((i << 1) + 1) << 6) + l) * 8);
      const b8 bh = *(const b8*)&Xh[ky][col + kx][qc];
      const b8 bl = *(const b8*)&Xl[ky][col + kx][qc];
      acc[0] = __builtin_amdgcn_mfma_f32_16x16x32_bf16(ah0, bh, acc[0], 0, 0, 0);
      acc[0] = __builtin_amdgcn_mfma_f32_16x16x32_bf16(ah0, bl, acc[0], 0, 0, 0);
      acc[0] = __builtin_amdgcn_mfma_f32_16x16x32_bf16(al0, bh, acc[0], 0, 0, 0);
      acc[1] = __builtin_amdgcn_mfma_f32_16x16x32_bf16(ah1, bh, acc[1], 0, 0, 0);
      acc[1] = __builtin_amdgcn_mfma_f32_16x16x32_bf16(ah1, bl, acc[1], 0, 0, 0);
      acc[1] = __builtin_amdgcn_mfma_f32_16x16x32_bf16(al1, bh, acc[1], 0, 0, 0);
    }
  }

  // store oc<18 (C layout: col=lane&15, row=(lane>>4)*4+reg)
  const int wo = col;
  const int q4 = (l >> 4) << 2;
#pragma unroll
  for (int mt = 0; mt < 2; ++mt)
#pragma unroll
    for (int r = 0; r < 4; ++r) {
      const int oc = (mt << 4) + q4 + r;
      if (oc < 18)
        ws[WS_OFFS + ((b * 18 + oc) << 12) + (ho << 6) + wo] = acc[mt][r];
    }
}

// ---------------------------------------------------------------------------
// K2: quad descriptors (unchanged from R6).
// ---------------------------------------------------------------------------
__global__ __launch_bounds__(256) void make_desc_k(
    const float* __restrict__ bof, float* __restrict__ ws) {
  const int d  = blockIdx.x * 256 + threadIdx.x;    // < 147456
  const int k  = d >> 14;
  const int n  = d & 16383;
  const int b  = n >> 12;
  const int sp = n & 4095;
  const int ho = sp >> 6, wo = sp & 63;
  const int ky = k / 3, kx = k - ky * 3;
  const float dy = ws[WS_OFFS + ((b * 18 + (k << 1)) << 12) + sp] + bof[k << 1];
  const float dx = ws[WS_OFFS + ((b * 18 + (k << 1) + 1) << 12) + sp] + bof[(k << 1) + 1];
  const float py = (float)(ho - 1 + ky) + dy;
  const float px = (float)(wo - 1 + kx) + dx;
  const float y0f = floorf(py), x0f = floorf(px);
  const float ly = py - y0f, lx = px - x0f;
  const int y0 = (int)y0f, x0 = (int)x0f;
  const int y1 = y0 + 1, x1 = x0 + 1;
  const float vy0 = (y0 >= 0 && y0 < 64) ? 1.f : 0.f;
  const float vy1 = (y1 >= 0 && y1 < 64) ? 1.f : 0.f;
  const float vx0 = (x0 >= 0 && x0 < 64) ? 1.f : 0.f;
  const float vx1 = (x1 >= 0 && x1 < 64) ? 1.f : 0.f;
  const int y0c = min(max(y0, 0), 63), y1c = min(max(y1, 0), 63);
  const int x0c = min(max(x0, 0), 63), x1c = min(max(x1, 0), 63);
  const float w00 = (1.f - ly) * (1.f - lx) * vy0 * vx0;
  const float w01 = (1.f - ly) * lx * vy0 * vx1;
  const float w10 = ly * (1.f - lx) * vy1 * vx0;
  const float w11 = ly * lx * vy1 * vx1;
  const int xf = min(x0c & ~1, 60);
  f4 g0 = {0.f, 0.f, 0.f, 0.f}, g1 = {0.f, 0.f, 0.f, 0.f};
#pragma unroll
  for (int j = 0; j < 4; ++j) {
    const int col = xf + j;
    g0[j] = (col == x0c ? w00 : 0.f) + (col == x1c ? w01 : 0.f);
    g1[j] = (col == x0c ? w10 : 0.f) + (col == x1c ? w11 : 0.f);
  }
  ((f4*)(ws + WS_GY0))[d] = g0;
  ((f4*)(ws + WS_GY1))[d] = g1;
  int2 ip; ip.x = (y0c << 6) + xf; ip.y = (y1c << 6) + xf;
  ((int2*)(ws + WS_IP))[d] = ip;
}

// ---------------------------------------------------------------------------
// K3: bf16 MFMA GEMM, fused deformable im2col.
// Grid 512 x 512 threads (8 waves): 2 blocks/CU -> 16 waves/CU (2x R6).
// Block tile 256(o) x 32(n); wave wv owns o [wv*32, wv*32+32) x all 32 n.
// A o-tiles loaded once per block-iter (disjoint wave slices); B samples
// gathered once device-wide. Per-lane combine = 2 channels (half of R6).
// ---------------------------------------------------------------------------
__global__ __launch_bounds__(512, 4) void deform_gemm_k(
    const float* __restrict__ x, const float* __restrict__ ws,
    float* __restrict__ out) {
  __shared__ ushort Bs[2][32][40];
  __shared__ f4   dG0[288];
  __shared__ f4   dG1[288];
  __shared__ int2 dIP[288];

  const int t     = threadIdx.x;
  const int bid   = blockIdx.x;
  const int xcd   = bid & 7;
  const int batch = xcd >> 1;
  const int j     = bid >> 3;                    // 0..63
  const int sp0   = ((((xcd & 1) << 6) + j) << 5);
  const int nd0   = (batch << 12) + sp0;
  const int l     = t & 63;
  const int wv    = t >> 6;                      // 0..7

  const int sn = t & 31;              // sample column 0..31
  const int cs = t >> 5;              // 2-ch slice 0..15
  const float* xb = x + ((long)batch << 20);
  const short* af = (const short*)(ws + WS_AFRAG);

  // ---- fill descriptor LDS (288 = 9k x 32 cols) ----
  if (t < 288) {
    const int kk = t >> 5, s = t & 31;
    const int dg = (kk << 14) + nd0 + s;
    dG0[t] = ((const f4*)(ws + WS_GY0))[dg];
    dG1[t] = ((const f4*)(ws + WS_GY1))[dg];
    dIP[t] = ((const int2*)(ws + WS_IP))[dg];
  }
  __syncthreads();

  f4 acc[2][2];
#pragma unroll
  for (int i = 0; i < 2; ++i)
#pragma unroll
    for (int q = 0; q < 2; ++q) acc[i][q] = f4{0.f, 0.f, 0.f, 0.f};

  const int otb = wv << 1;            // wave's first o-tile (2 per wave)
  b8 aA[2], aN[2];
  f4 g0, g1; int p0, p1;              // descriptor for pending gather
  f4u r00, r01, r10, r11;             // [ch][row] gathered quads

#define RDDESC(KK_) do { const int u_ = ((KK_) << 5) + sn;                   \
    g0 = dG0[u_]; g1 = dG1[u_];                                              \
    const int2 ip_ = dIP[u_]; p0 = ip_.x; p1 = ip_.y; } while (0)

#define GATHER(CG_) do {                                                     \
    const int c0_ = ((CG_) << 5) + (cs << 1);                                \
    const float* pl0_ = xb + ((long)c0_ << 12);                              \
    const float* pl1_ = pl0_ + 4096;                                         \
    r00 = *(const f4u*)(pl0_ + p0);  r01 = *(const f4u*)(pl0_ + p1);         \
    r10 = *(const f4u*)(pl1_ + p0);  r11 = *(const f4u*)(pl1_ + p1);         \
  } while (0)

#define COMBINE(BUF_) do {                                                   \
    const float v0_ = g0.x * r00.x + g0.y * r00.y + g0.z * r00.z +           \
                      g0.w * r00.w + g1.x * r01.x + g1.y * r01.y +           \
                      g1.z * r01.z + g1.w * r01.w;                           \
    const float v1_ = g0.x * r10.x + g0.y * r10.y + g0.z * r10.z +           \
                      g0.w * r10.w + g1.x * r11.x + g1.y * r11.y +           \
                      g1.z * r11.z + g1.w * r11.w;                           \
    ushort2 pk_; pk_.x = f2bf(v0_); pk_.y = f2bf(v1_);                       \
    *(ushort2*)&Bs[BUF_][sn][cs << 1] = pk_; } while (0)

#define LOADA(I_, DST_) do {                                                 \
    _Pragma("unroll")                                                        \
    for (int m = 0; m < 2; ++m)                                              \
      DST_[m] = *(const b8*)(af + (((((I_) << 4) + otb + m) << 6) + l) * 8); \
  } while (0)

  // prologue: iter 0 = (cg0, kk0)
  RDDESC(0);
  GATHER(0);
  LOADA(0, aA);
  COMBINE(0);
  RDDESC(1);                          // desc for iter 1
  __syncthreads();

  int kkN = 1, cgN = 0;               // (kk, cg) of iter i+1
  for (int i = 0; i < 72; ++i) {
    const int cur = i & 1;
    if (i < 71) {
      GATHER(cgN);                    // gather for iter i+1 (desc in g/p)
      LOADA(i + 1, aN);
    }
    b8 bB[2];
#pragma unroll
    for (int nt = 0; nt < 2; ++nt)
      bB[nt] = *(const b8*)&Bs[cur][(nt << 4) + (l & 15)][(l >> 4) << 3];
#pragma unroll
    for (int mt = 0; mt < 2; ++mt)
#pragma unroll
      for (int nt = 0; nt < 2; ++nt)
        acc[mt][nt] = __builtin_amdgcn_mfma_f32_16x16x32_bf16(
            aA[mt], bB[nt], acc[mt][nt], 0, 0, 0);
    if (i < 71) {
      COMBINE(cur ^ 1);
      kkN++; if (kkN == 9) { kkN = 0; cgN++; }
      if (i < 70) RDDESC(kkN);
#pragma unroll
      for (int m = 0; m < 2; ++m) aA[m] = aN[m];
    }
    __syncthreads();
  }

  const float* bfold = ws + WS_BFOLD;
  const int q4 = (l >> 4) << 2;
  const int ow = wv << 5;
#pragma unroll
  for (int mt = 0; mt < 2; ++mt) {
    const int ob = ow + (mt << 4) + q4;
    const f4 bf = *(const f4*)&bfold[ob];
#pragma unroll
    for (int nt = 0; nt < 2; ++nt) {
      const int sp = sp0 + (nt << 4) + (l & 15);
#pragma unroll
      for (int r = 0; r < 4; ++r) {
        const int o = ob + r;
        out[(((batch << 8) + o) << 12) + sp] =
            fmaxf(acc[mt][nt][r] + bf[r], 0.f);
      }
    }
  }
}

// ---------------------------------------------------------------------------
extern "C" void kernel_launch(void* const* d_in, const int* in_sizes, int n_in,
                              void* d_out, int out_size, void* d_ws, size_t ws_size,
                              hipStream_t stream) {
  const float* x     = (const float*)d_in[0];
  const float* wof   = (const float*)d_in[1];
  const float* bof   = (const float*)d_in[2];
  const float* w     = (const float*)d_in[3];
  const float* bias  = (const float*)d_in[4];
  const float* gamma = (const float*)d_in[5];
  const float* beta  = (const float*)d_in[6];
  const float* mean  = (const float*)d_in[7];
  const float* var   = (const float*)d_in[8];
  float* out = (float*)d_out;
  float* ws  = (float*)d_ws;

  hipLaunchKernelGGL(prep_k, dim3(288), dim3(256), 0, stream,
                     w, wof, bias, gamma, beta, mean, var, ws);
  hipLaunchKernelGGL(offset_mfma_k, dim3(256), dim3(256), 0, stream,
                     x, ws);
  hipLaunchKernelGGL(make_desc_k, dim3(576), dim3(256), 0, stream,
                     bof, ws);
  hipLaunchKernelGGL(deform_gemm_k, dim3(512), dim3(512), 0, stream,
                     x, ws, out);
}

// Round 8
// 199.200 us; speedup vs baseline: 1.6193x; 1.0881x over previous
//
#include <hip/hip_runtime.h>
#include <math.h>

typedef __attribute__((ext_vector_type(8))) short b8;
typedef __attribute__((ext_vector_type(4))) short s4;
typedef __attribute__((ext_vector_type(4))) float f4;
typedef __attribute__((ext_vector_type(4))) int i4;
typedef float f4u __attribute__((ext_vector_type(4), aligned(4)));  // align-4 float4

// ---------------- fallback (R7) ws layout (float offsets) ------------------
#define WS_OFFS   0                 // 294912 (B*18*HW)
#define WS_GY0    294912            // float4[147456]
#define WS_GY1    884736
#define WS_IP     1474560           // int2[147456]
#define WS_AFRAG  1769472           // bf16[589824]
#define WS_BFOLD  2064384
#define WS_K1WH   294912            // overlay in GY0 (prep->K1, then K2 overwrites)
#define WS_K1WL   331776
// fallback total 2064640 floats = 8,258,560 B (known-good)

// ---------------- big-ws (XT) layout (float offsets) -----------------------
#define XT2   0                     // bf16[4*4096*256] = 2097152 floats
#define OF2   2097152               // 294912
#define DW2   2392064               // f4[147456] = 589824 floats (weights)
#define DP2   2981888               // i4[147456] = 589824 floats (corner positions)
#define AF2   3571712               // 294912
#define BF2   3866624               // 256
#define WH2   2392064               // overlay in DW2
#define WL2   2428928
#define XT_TOTAL_BYTES (3866880u * 4u)   // 15,467,520

__device__ inline ushort f2bf(float f) {
  uint u = __float_as_uint(f);
  return (ushort)((u + 0x7FFFu + ((u >> 16) & 1u)) >> 16);   // RNE
}
__device__ inline float bf2f(short s) {
  return __uint_as_float(((uint)(ushort)s) << 16);
}

// ---------------------------------------------------------------------------
// prep (shared): (a) main A-frags (weight*BN, bf16) in (cg,kk) iter order;
// (b) folded bias; (c) K1 offset-conv A-frags, bf16 split, M padded 18->32.
// Region offsets passed per-path.
// ---------------------------------------------------------------------------
__global__ __launch_bounds__(256) void prep_k(
    const float* __restrict__ w, const float* __restrict__ wof,
    const float* __restrict__ bias,
    const float* __restrict__ gamma, const float* __restrict__ beta,
    const float* __restrict__ mean, const float* __restrict__ var,
    float* __restrict__ ws, int AF, int BF, int WH, int WL) {
  const int tid = blockIdx.x * 256 + threadIdx.x;    // < 73728
  const int l  = tid & 63;
  const int ot = (tid >> 6) & 15;
  const int i  = tid >> 10;          // 0..71
  const int cg = i / 9;
  const int kk = i - cg * 9;
  const int o  = (ot << 4) + (l & 15);
  const int cb = (cg << 5) + ((l >> 4) << 3);
  const float inv = gamma[o] * rsqrtf(var[o] + 1e-5f);
  b8 pk;
#pragma unroll
  for (int j = 0; j < 8; ++j)
    pk[j] = (short)f2bf(w[((o << 8) + cb + j) * 9 + kk] * inv);
  *(b8*)((short*)(ws + AF) + tid * 8) = pk;
  if (tid < 256) {
    const float iv = gamma[tid] * rsqrtf(var[tid] + 1e-5f);
    ws[BF + tid] = bias[tid] * iv + beta[tid] - mean[tid] * iv;
  }
  if (tid < 9216) {
    const int l2  = tid & 63;
    const int mt  = (tid >> 6) & 1;
    const int i2  = tid >> 7;        // 0..71
    const int cg2 = i2 / 9;
    const int kk2 = i2 - cg2 * 9;
    const int oc  = (mt << 4) + (l2 & 15);
    const int cb2 = (cg2 << 5) + ((l2 >> 4) << 3);
    b8 ph, pl;
#pragma unroll
    for (int j = 0; j < 8; ++j) {
      const float v = (oc < 18) ? wof[((oc << 8) + cb2 + j) * 9 + kk2] : 0.f;
      const ushort h = f2bf(v);
      const float hf = __uint_as_float((uint)h << 16);
      ph[j] = (short)h;
      pl[j] = (short)f2bf(v - hf);
    }
    *(b8*)((short*)(ws + WH) + tid * 8) = ph;
    *(b8*)((short*)(ws + WL) + tid * 8) = pl;
  }
}

// ---------------------------------------------------------------------------
// transpose (XT path): x (B,C,H,W) fp32 -> xt (B,P,C) bf16.
// unit id = ((b*32+cg8)<<12)+p; lanes consecutive p -> coalesced reads;
// each thread: 8 strided reads, 1 contiguous 16B store.
// ---------------------------------------------------------------------------
__global__ __launch_bounds__(256) void transpose_k(
    const float* __restrict__ x, float* __restrict__ ws) {
  const int id  = blockIdx.x * 256 + threadIdx.x;   // < 524288
  const int p   = id & 4095;
  const int cg8 = (id >> 12) & 31;
  const int b   = id >> 17;
  const float* xp = x + (((long)(b * 256 + cg8 * 8)) << 12) + p;
  ushort* xt = (ushort*)(ws + XT2);
  b8 pk;
#pragma unroll
  for (int j = 0; j < 8; ++j) pk[j] = (short)f2bf(xp[(long)j << 12]);
  *(b8*)(xt + ((((long)(b << 12) + p)) << 8) + (cg8 << 3)) = pk;
}

// ---------------------------------------------------------------------------
// K1 (shared): offset conv as bf16-split MFMA GEMM. Grid 256 = (b<<6)|ho.
// ---------------------------------------------------------------------------
__global__ __launch_bounds__(256) void offset_mfma_k(
    const float* __restrict__ x, float* __restrict__ ws,
    int OFFS, int WH, int WL) {
  __shared__ __align__(16) ushort Xh[3][66][40];
  __shared__ __align__(16) ushort Xl[3][66][40];
  const int bid = blockIdx.x;
  const int b   = bid >> 6;
  const int ho  = bid & 63;
  const int t   = threadIdx.x;
  const int l   = t & 63;
  const int wv  = t >> 6;
  const short* afh = (const short*)(ws + WH);
  const short* afl = (const short*)(ws + WL);

  for (int u = t; u < 240; u += 256) {
    const int row = u / 80, rem = u % 80;
    const int col = (rem >= 40) ? 65 : 0;
    const int c   = rem % 40;
    Xh[row][col][c] = 0;
    Xl[row][col][c] = 0;
  }

  f4 acc[2];
  acc[0] = f4{0.f, 0.f, 0.f, 0.f};
  acc[1] = f4{0.f, 0.f, 0.f, 0.f};

  const int cidx = t >> 3;
  const int j8   = t & 7;
  const float* xc = x + ((long)b << 20) + ((long)cidx << 12);
  const int col = (wv << 4) + (l & 15);
  const int qc  = (l >> 4) << 3;

  for (int cg = 0; cg < 8; ++cg) {
    __syncthreads();
    const float* xg = xc + ((long)(cg << 5) << 12);
#pragma unroll
    for (int rep = 0; rep < 6; ++rep) {
      const int fi   = (rep << 3) + j8;
      const int row  = fi >> 4;
      const int colf = (fi & 15) << 2;
      const int y = ho - 1 + row;
      f4u v = {0.f, 0.f, 0.f, 0.f};
      if (y >= 0 && y <= 63) v = *(const f4u*)(xg + (y << 6) + colf);
#pragma unroll
      for (int q = 0; q < 4; ++q) {
        const ushort h = f2bf(v[q]);
        const float hf = __uint_as_float((uint)h << 16);
        Xh[row][colf + 1 + q][cidx] = h;
        Xl[row][colf + 1 + q][cidx] = f2bf(v[q] - hf);
      }
    }
    __syncthreads();
#pragma unroll
    for (int kk = 0; kk < 9; ++kk) {
      const int ky = kk / 3, kx = kk - ky * 3;
      const int i  = cg * 9 + kk;
      const b8 ah0 = *(const b8*)(afh + ((((i << 1) + 0) << 6) + l) * 8);
      const b8 ah1 = *(const b8*)(afh + ((((i << 1) + 1) << 6) + l) * 8);
      const b8 al0 = *(const b8*)(afl + ((((i << 1) + 0) << 6) + l) * 8);
      const b8 al1 = *(const b8*)(afl + ((((i << 1) + 1) << 6) + l) * 8);
      const b8 bh = *(const b8*)&Xh[ky][col + kx][qc];
      const b8 bl = *(const b8*)&Xl[ky][col + kx][qc];
      acc[0] = __builtin_amdgcn_mfma_f32_16x16x32_bf16(ah0, bh, acc[0], 0, 0, 0);
      acc[0] = __builtin_amdgcn_mfma_f32_16x16x32_bf16(ah0, bl, acc[0], 0, 0, 0);
      acc[0] = __builtin_amdgcn_mfma_f32_16x16x32_bf16(al0, bh, acc[0], 0, 0, 0);
      acc[1] = __builtin_amdgcn_mfma_f32_16x16x32_bf16(ah1, bh, acc[1], 0, 0, 0);
      acc[1] = __builtin_amdgcn_mfma_f32_16x16x32_bf16(ah1, bl, acc[1], 0, 0, 0);
      acc[1] = __builtin_amdgcn_mfma_f32_16x16x32_bf16(al1, bh, acc[1], 0, 0, 0);
    }
  }

  const int wo = col;
  const int q4 = (l >> 4) << 2;
#pragma unroll
  for (int mt = 0; mt < 2; ++mt)
#pragma unroll
    for (int r = 0; r < 4; ++r) {
      const int oc = (mt << 4) + q4 + r;
      if (oc < 18)
        ws[OFFS + ((b * 18 + oc) << 12) + (ho << 6) + wo] = acc[mt][r];
    }
}

// ---------------------------------------------------------------------------
// descriptor math (shared inline)
// ---------------------------------------------------------------------------
struct DescOut {
  float w00, w01, w10, w11;
  int y0c, y1c, x0c, x1c;
};
__device__ inline DescOut desc_math(const float* ws, const float* bof,
                                    int OFFS, int d) {
  const int k  = d >> 14;
  const int n  = d & 16383;
  const int b  = n >> 12;
  const int sp = n & 4095;
  const int ho = sp >> 6, wo = sp & 63;
  const int ky = k / 3, kx = k - ky * 3;
  const float dy = ws[OFFS + ((b * 18 + (k << 1)) << 12) + sp] + bof[k << 1];
  const float dx = ws[OFFS + ((b * 18 + (k << 1) + 1) << 12) + sp] + bof[(k << 1) + 1];
  const float py = (float)(ho - 1 + ky) + dy;
  const float px = (float)(wo - 1 + kx) + dx;
  const float y0f = floorf(py), x0f = floorf(px);
  const float ly = py - y0f, lx = px - x0f;
  const int y0 = (int)y0f, x0 = (int)x0f;
  const int y1 = y0 + 1, x1 = x0 + 1;
  const float vy0 = (y0 >= 0 && y0 < 64) ? 1.f : 0.f;
  const float vy1 = (y1 >= 0 && y1 < 64) ? 1.f : 0.f;
  const float vx0 = (x0 >= 0 && x0 < 64) ? 1.f : 0.f;
  const float vx1 = (x1 >= 0 && x1 < 64) ? 1.f : 0.f;
  DescOut o;
  o.y0c = min(max(y0, 0), 63); o.y1c = min(max(y1, 0), 63);
  o.x0c = min(max(x0, 0), 63); o.x1c = min(max(x1, 0), 63);
  o.w00 = (1.f - ly) * (1.f - lx) * vy0 * vx0;
  o.w01 = (1.f - ly) * lx * vy0 * vx1;
  o.w10 = ly * (1.f - lx) * vy1 * vx0;
  o.w11 = ly * lx * vy1 * vx1;
  return o;
}

// ---------------------------------------------------------------------------
// K2 fallback (R7 quad-descriptor form)
// ---------------------------------------------------------------------------
__global__ __launch_bounds__(256) void make_desc_k(
    const float* __restrict__ bof, float* __restrict__ ws) {
  const int d = blockIdx.x * 256 + threadIdx.x;
  DescOut q = desc_math(ws, bof, WS_OFFS, d);
  const int xf = min(q.x0c & ~1, 60);
  f4 g0 = {0.f, 0.f, 0.f, 0.f}, g1 = {0.f, 0.f, 0.f, 0.f};
#pragma unroll
  for (int j = 0; j < 4; ++j) {
    const int col = xf + j;
    g0[j] = (col == q.x0c ? q.w00 : 0.f) + (col == q.x1c ? q.w01 : 0.f);
    g1[j] = (col == q.x0c ? q.w10 : 0.f) + (col == q.x1c ? q.w11 : 0.f);
  }
  ((f4*)(ws + WS_GY0))[d] = g0;
  ((f4*)(ws + WS_GY1))[d] = g1;
  int2 ip; ip.x = (q.y0c << 6) + xf; ip.y = (q.y1c << 6) + xf;
  ((int2*)(ws + WS_IP))[d] = ip;
}

// ---------------------------------------------------------------------------
// K2 XT: 4 weights + 4 full corner positions
// ---------------------------------------------------------------------------
__global__ __launch_bounds__(256) void make_desc_xt(
    const float* __restrict__ bof, float* __restrict__ ws) {
  const int d = blockIdx.x * 256 + threadIdx.x;
  DescOut q = desc_math(ws, bof, OF2, d);
  f4 wv; wv.x = q.w00; wv.y = q.w01; wv.z = q.w10; wv.w = q.w11;
  i4 pv;
  pv.x = (q.y0c << 6) + q.x0c;
  pv.y = (q.y0c << 6) + q.x1c;
  pv.z = (q.y1c << 6) + q.x0c;
  pv.w = (q.y1c << 6) + q.x1c;
  ((f4*)(ws + DW2))[d] = wv;
  ((i4*)(ws + DP2))[d] = pv;
}

// ---------------------------------------------------------------------------
// K3 fallback: R7 gemm verbatim
// ---------------------------------------------------------------------------
__global__ __launch_bounds__(512, 4) void deform_gemm_k(
    const float* __restrict__ x, const float* __restrict__ ws,
    float* __restrict__ out) {
  __shared__ ushort Bs[2][32][40];
  __shared__ f4   dG0[288];
  __shared__ f4   dG1[288];
  __shared__ int2 dIP[288];

  const int t     = threadIdx.x;
  const int bid   = blockIdx.x;
  const int xcd   = bid & 7;
  const int batch = xcd >> 1;
  const int j     = bid >> 3;
  const int sp0   = ((((xcd & 1) << 6) + j) << 5);
  const int nd0   = (batch << 12) + sp0;
  const int l     = t & 63;
  const int wv    = t >> 6;

  const int sn = t & 31;
  const int cs = t >> 5;
  const float* xb = x + ((long)batch << 20);
  const short* af = (const short*)(ws + WS_AFRAG);

  if (t < 288) {
    const int kk = t >> 5, s = t & 31;
    const int dg = (kk << 14) + nd0 + s;
    dG0[t] = ((const f4*)(ws + WS_GY0))[dg];
    dG1[t] = ((const f4*)(ws + WS_GY1))[dg];
    dIP[t] = ((const int2*)(ws + WS_IP))[dg];
  }
  __syncthreads();

  f4 acc[2][2];
#pragma unroll
  for (int i = 0; i < 2; ++i)
#pragma unroll
    for (int q = 0; q < 2; ++q) acc[i][q] = f4{0.f, 0.f, 0.f, 0.f};

  const int otb = wv << 1;
  b8 aA[2], aN[2];
  f4 g0, g1; int p0, p1;
  f4u r00, r01, r10, r11;

#define RDDESC(KK_) do { const int u_ = ((KK_) << 5) + sn;                   \
    g0 = dG0[u_]; g1 = dG1[u_];                                              \
    const int2 ip_ = dIP[u_]; p0 = ip_.x; p1 = ip_.y; } while (0)

#define GATHER(CG_) do {                                                     \
    const int c0_ = ((CG_) << 5) + (cs << 1);                                \
    const float* pl0_ = xb + ((long)c0_ << 12);                              \
    const float* pl1_ = pl0_ + 4096;                                         \
    r00 = *(const f4u*)(pl0_ + p0);  r01 = *(const f4u*)(pl0_ + p1);         \
    r10 = *(const f4u*)(pl1_ + p0);  r11 = *(const f4u*)(pl1_ + p1);         \
  } while (0)

#define COMBINE(BUF_) do {                                                   \
    const float v0_ = g0.x * r00.x + g0.y * r00.y + g0.z * r00.z +           \
                      g0.w * r00.w + g1.x * r01.x + g1.y * r01.y +           \
                      g1.z * r01.z + g1.w * r01.w;                           \
    const float v1_ = g0.x * r10.x + g0.y * r10.y + g0.z * r10.z +           \
                      g0.w * r10.w + g1.x * r11.x + g1.y * r11.y +           \
                      g1.z * r11.z + g1.w * r11.w;                           \
    ushort2 pk_; pk_.x = f2bf(v0_); pk_.y = f2bf(v1_);                       \
    *(ushort2*)&Bs[BUF_][sn][cs << 1] = pk_; } while (0)

#define LOADA(I_, DST_) do {                                                 \
    _Pragma("unroll")                                                        \
    for (int m = 0; m < 2; ++m)                                              \
      DST_[m] = *(const b8*)(af + (((((I_) << 4) + otb + m) << 6) + l) * 8); \
  } while (0)

  RDDESC(0);
  GATHER(0);
  LOADA(0, aA);
  COMBINE(0);
  RDDESC(1);
  __syncthreads();

  int kkN = 1, cgN = 0;
  for (int i = 0; i < 72; ++i) {
    const int cur = i & 1;
    if (i < 71) {
      GATHER(cgN);
      LOADA(i + 1, aN);
    }
    b8 bB[2];
#pragma unroll
    for (int nt = 0; nt < 2; ++nt)
      bB[nt] = *(const b8*)&Bs[cur][(nt << 4) + (l & 15)][(l >> 4) << 3];
#pragma unroll
    for (int mt = 0; mt < 2; ++mt)
#pragma unroll
      for (int nt = 0; nt < 2; ++nt)
        acc[mt][nt] = __builtin_amdgcn_mfma_f32_16x16x32_bf16(
            aA[mt], bB[nt], acc[mt][nt], 0, 0, 0);
    if (i < 71) {
      COMBINE(cur ^ 1);
      kkN++; if (kkN == 9) { kkN = 0; cgN++; }
      if (i < 70) RDDESC(kkN);
#pragma unroll
      for (int m = 0; m < 2; ++m) aA[m] = aN[m];
    }
    __syncthreads();
  }
#undef RDDESC
#undef GATHER
#undef COMBINE
#undef LOADA

  const float* bfold = ws + WS_BFOLD;
  const int q4 = (l >> 4) << 2;
  const int ow = wv << 5;
#pragma unroll
  for (int mt = 0; mt < 2; ++mt) {
    const int ob = ow + (mt << 4) + q4;
    const f4 bf = *(const f4*)&bfold[ob];
#pragma unroll
    for (int nt = 0; nt < 2; ++nt) {
      const int sp = sp0 + (nt << 4) + (l & 15);
#pragma unroll
      for (int r = 0; r < 4; ++r) {
        const int o = ob + r;
        out[(((batch << 8) + o) << 12) + sp] =
            fmaxf(acc[mt][nt][r] + bf[r], 0.f);
      }
    }
  }
}

// ---------------------------------------------------------------------------
// K3 XT: bf16 MFMA GEMM with channel-contiguous bf16 gathers.
// Grid 256 (1/CU), 256 threads (4 waves). Tile 256o x 64n; wave = 64o x 64n.
// Gather unit = (sample, 8ch): 4 corner b8 loads; lanes (16 sn x 4 cg8)
// -> 16 cache lines per gather wave-instr.
// ---------------------------------------------------------------------------
__global__ __launch_bounds__(256) void deform_gemm_xt(
    const float* __restrict__ ws, float* __restrict__ out) {
  __shared__ ushort Bs[2][64][40];   // 10 KB
  __shared__ f4 dW[576];             // 9 KB
  __shared__ i4 dP[576];             // 9 KB

  const int t     = threadIdx.x;
  const int bid   = blockIdx.x;
  const int xcd   = bid & 7;
  const int batch = xcd >> 1;
  const int half  = xcd & 1;
  const int slot  = bid >> 3;                    // 0..31
  const int sp0   = (half << 11) + (slot << 6);
  const int nd0   = (batch << 12) + sp0;
  const int l     = t & 63;
  const int wv    = t >> 6;

  const int sn  = t >> 2;             // 0..63
  const int cg8 = t & 3;              // 8-ch group within 32-ch window
  const ushort* xtb = (const ushort*)(ws + XT2) + (((long)batch << 12) << 8);
  const short* af = (const short*)(ws + AF2);

  // fill descriptor LDS: 576 = 9 kk x 64 samples
  for (int u = t; u < 576; u += 256) {
    const int kk = u >> 6, s = u & 63;
    const int dg = (kk << 14) + nd0 + s;
    dW[u] = ((const f4*)(ws + DW2))[dg];
    dP[u] = ((const i4*)(ws + DP2))[dg];
  }
  __syncthreads();

  f4 acc[4][4];
#pragma unroll
  for (int i = 0; i < 4; ++i)
#pragma unroll
    for (int q = 0; q < 4; ++q) acc[i][q] = f4{0.f, 0.f, 0.f, 0.f};

  const int otb = wv << 2;            // wave's first of 4 o-tiles
  b8 aA[4], aN[4];
  f4 gw; i4 gp;
  b8 c00, c01, c10, c11;

#define XRDDESC(KK_) do { const int u_ = ((KK_) << 6) + sn;                  \
    gw = dW[u_]; gp = dP[u_]; } while (0)

#define XGATHER(CG_) do {                                                    \
    const int co_ = ((CG_) << 5) + (cg8 << 3);                               \
    c00 = *(const b8*)(xtb + (gp.x << 8) + co_);                             \
    c01 = *(const b8*)(xtb + (gp.y << 8) + co_);                             \
    c10 = *(const b8*)(xtb + (gp.z << 8) + co_);                             \
    c11 = *(const b8*)(xtb + (gp.w << 8) + co_); } while (0)

#define XCOMBINE(BUF_) do { b8 pk_;                                          \
    _Pragma("unroll")                                                        \
    for (int q = 0; q < 8; ++q) {                                            \
      const float v_ = gw.x * bf2f(c00[q]) + gw.y * bf2f(c01[q]) +           \
                       gw.z * bf2f(c10[q]) + gw.w * bf2f(c11[q]);            \
      pk_[q] = (short)f2bf(v_);                                              \
    }                                                                        \
    *(b8*)&Bs[BUF_][sn][cg8 << 3] = pk_; } while (0)

#define XLOADA(I_, DST_) do {                                                \
    _Pragma("unroll")                                                        \
    for (int m = 0; m < 4; ++m)                                              \
      DST_[m] = *(const b8*)(af + (((((I_) << 4) + otb + m) << 6) + l) * 8); \
  } while (0)

  XRDDESC(0);
  XGATHER(0);
  XLOADA(0, aA);
  XCOMBINE(0);
  XRDDESC(1);
  __syncthreads();

  int kkN = 1, cgN = 0;               // (kk,cg) of iter i+1
  for (int i = 0; i < 72; ++i) {
    const int cur = i & 1;
    if (i < 71) {
      XGATHER(cgN);
      XLOADA(i + 1, aN);
    }
    b8 bB[4];
#pragma unroll
    for (int nt = 0; nt < 4; ++nt)
      bB[nt] = *(const b8*)&Bs[cur][(nt << 4) + (l & 15)][(l >> 4) << 3];
#pragma unroll
    for (int mt = 0; mt < 4; ++mt)
#pragma unroll
      for (int nt = 0; nt < 4; ++nt)
        acc[mt][nt] = __builtin_amdgcn_mfma_f32_16x16x32_bf16(
            aA[mt], bB[nt], acc[mt][nt], 0, 0, 0);
    if (i < 71) {
      XCOMBINE(cur ^ 1);
      kkN++; if (kkN == 9) { kkN = 0; cgN++; }
      if (i < 70) XRDDESC(kkN);
#pragma unroll
      for (int m = 0; m < 4; ++m) aA[m] = aN[m];
    }
    __syncthreads();
  }

  const float* bfold = ws + BF2;
  const int q4 = (l >> 4) << 2;
  const int ow = wv << 6;
#pragma unroll
  for (int mt = 0; mt < 4; ++mt) {
    const int ob = ow + (mt << 4) + q4;
    const f4 bf = *(const f4*)&bfold[ob];
#pragma unroll
    for (int nt = 0; nt < 4; ++nt) {
      const int sp = sp0 + (nt << 4) + (l & 15);
#pragma unroll
      for (int r = 0; r < 4; ++r) {
        const int o = ob + r;
        out[(((batch << 8) + o) << 12) + sp] =
            fmaxf(acc[mt][nt][r] + bf[r], 0.f);
      }
    }
  }
}

// ---------------------------------------------------------------------------
extern "C" void kernel_launch(void* const* d_in, const int* in_sizes, int n_in,
                              void* d_out, int out_size, void* d_ws, size_t ws_size,
                              hipStream_t stream) {
  const float* x     = (const float*)d_in[0];
  const float* wof   = (const float*)d_in[1];
  const float* bof   = (const float*)d_in[2];
  const float* w     = (const float*)d_in[3];
  const float* bias  = (const float*)d_in[4];
  const float* gamma = (const float*)d_in[5];
  const float* beta  = (const float*)d_in[6];
  const float* mean  = (const float*)d_in[7];
  const float* var   = (const float*)d_in[8];
  float* out = (float*)d_out;
  float* ws  = (float*)d_ws;

  const bool big = ws_size >= (size_t)XT_TOTAL_BYTES;
  if (big) {
    hipLaunchKernelGGL(prep_k, dim3(288), dim3(256), 0, stream,
                       w, wof, bias, gamma, beta, mean, var, ws,
                       AF2, BF2, WH2, WL2);
    hipLaunchKernelGGL(transpose_k, dim3(2048), dim3(256), 0, stream, x, ws);
    hipLaunchKernelGGL(offset_mfma_k, dim3(256), dim3(256), 0, stream,
                       x, ws, OF2, WH2, WL2);
    hipLaunchKernelGGL(make_desc_xt, dim3(576), dim3(256), 0, stream, bof, ws);
    hipLaunchKernelGGL(deform_gemm_xt, dim3(256), dim3(256), 0, stream,
                       ws, out);
  } else {
    hipLaunchKernelGGL(prep_k, dim3(288), dim3(256), 0, stream,
                       w, wof, bias, gamma, beta, mean, var, ws,
                       WS_AFRAG, WS_BFOLD, WS_K1WH, WS_K1WL);
    hipLaunchKernelGGL(offset_mfma_k, dim3(256), dim3(256), 0, stream,
                       x, ws, WS_OFFS, WS_K1WH, WS_K1WL);
    hipLaunchKernelGGL(make_desc_k, dim3(576), dim3(256), 0, stream, bof, ws);
    hipLaunchKernelGGL(deform_gemm_k, dim3(512), dim3(512), 0, stream,
                       x, ws, out);
  }
}

// Round 9
// 162.972 us; speedup vs baseline: 1.9793x; 1.2223x over previous
//
#include <hip/hip_runtime.h>
#include <math.h>

typedef __attribute__((ext_vector_type(8))) short b8;
typedef __attribute__((ext_vector_type(4))) short s4;
typedef __attribute__((ext_vector_type(4))) float f4;
typedef __attribute__((ext_vector_type(4))) int i4;
typedef float f4u __attribute__((ext_vector_type(4), aligned(4)));  // align-4 float4
typedef _Float16 h8 __attribute__((ext_vector_type(8)));
typedef _Float16 h2 __attribute__((ext_vector_type(2)));

// ---------------- fallback (R7) ws layout (float offsets) ------------------
#define WS_OFFS   0                 // 294912 (B*18*HW)
#define WS_GY0    294912            // float4[147456]
#define WS_GY1    884736
#define WS_IP     1474560           // int2[147456]
#define WS_AFRAG  1769472           // bf16[589824]
#define WS_BFOLD  2064384
#define WS_K1WH   294912            // overlay in GY0 (prep->K1, then K2 overwrites)
#define WS_K1WL   331776
// fallback total 2064640 floats = 8,258,560 B (known-good)

// ---------------- big-ws (XT) layout (float offsets) -----------------------
#define XT2   0                     // f16[4*4096*256] = 2097152 floats
#define OF2   2097152               // 294912 (fp32 accumulated offsets)
#define DW2   2392064               // uint4[147456] = 589824 floats (half2-dup weights)
#define DP2   2981888               // int4[147456] = 589824 floats (corner positions)
#define AF2   3571712               // f16[589824] = 294912 floats
#define BF2   3866624               // 256
#define WH2   2392064               // overlay in DW2 (prep->offset, desc overwrites)
#define WL2   2428928
#define XT_TOTAL_BYTES (3866880u * 4u)   // 15,467,520

__device__ inline ushort f2bf(float f) {
  uint u = __float_as_uint(f);
  return (ushort)((u + 0x7FFFu + ((u >> 16) & 1u)) >> 16);   // RNE
}
__device__ inline float bf2f(short s) {
  return __uint_as_float(((uint)(ushort)s) << 16);
}
__device__ inline h2 u2h2(uint u) { union { uint u; h2 h; } x; x.u = u; return x.h; }
__device__ inline uint h22u(h2 h) { union { uint u; h2 h; } x; x.h = h; return x.u; }
__device__ inline uint duph(float f) {
  union { _Float16 h; ushort u; } x; x.h = (_Float16)f;
  return ((uint)x.u << 16) | x.u;
}

// ---------------------------------------------------------------------------
// prep: (a) main A-frags (weight*BN) in iteration order — mode 0: bf16, old
// (cg32,kk) order; mode 1: f16, (cw64,kk,s) order + zero the OF2 accumulator;
// (b) folded bias; (c) K1 offset-conv A-frags, bf16 split, M padded 18->32.
// ---------------------------------------------------------------------------
__global__ __launch_bounds__(256) void prep_k(
    const float* __restrict__ w, const float* __restrict__ wof,
    const float* __restrict__ bias,
    const float* __restrict__ gamma, const float* __restrict__ beta,
    const float* __restrict__ mean, const float* __restrict__ var,
    float* __restrict__ ws, int AF, int BF, int WH, int WL, int mode) {
  const int tid = blockIdx.x * 256 + threadIdx.x;    // < 73728
  const int l  = tid & 63;
  const int ot = (tid >> 6) & 15;
  const int f  = tid >> 10;          // 0..71
  const int o  = (ot << 4) + (l & 15);
  const float inv = gamma[o] * rsqrtf(var[o] + 1e-5f);
  if (mode == 0) {
    const int cg = f / 9;
    const int kk = f - cg * 9;
    const int cb = (cg << 5) + ((l >> 4) << 3);
    b8 pk;
#pragma unroll
    for (int j = 0; j < 8; ++j)
      pk[j] = (short)f2bf(w[((o << 8) + cb + j) * 9 + kk] * inv);
    *(b8*)((short*)(ws + AF) + tid * 8) = pk;
  } else {
    const int s  = f & 1;
    const int g  = f >> 1;           // 0..35
    const int cw = g / 9;
    const int kk = g - cw * 9;
    const int cb = (cw << 6) + (s << 5) + ((l >> 4) << 3);
    h8 pk;
#pragma unroll
    for (int j = 0; j < 8; ++j)
      pk[j] = (_Float16)(w[((o << 8) + cb + j) * 9 + kk] * inv);
    *(h8*)((_Float16*)(ws + AF) + tid * 8) = pk;
    // zero the offset accumulator (294912 floats = 73728 f4)
    ((f4*)(ws + OF2))[tid] = f4{0.f, 0.f, 0.f, 0.f};
  }
  if (tid < 256) {
    const float iv = gamma[tid] * rsqrtf(var[tid] + 1e-5f);
    ws[BF + tid] = bias[tid] * iv + beta[tid] - mean[tid] * iv;
  }
  if (tid < 9216) {
    const int l2  = tid & 63;
    const int mt  = (tid >> 6) & 1;
    const int i2  = tid >> 7;        // 0..71
    const int cg2 = i2 / 9;
    const int kk2 = i2 - cg2 * 9;
    const int oc  = (mt << 4) + (l2 & 15);
    const int cb2 = (cg2 << 5) + ((l2 >> 4) << 3);
    b8 ph, pl;
#pragma unroll
    for (int j = 0; j < 8; ++j) {
      const float v = (oc < 18) ? wof[((oc << 8) + cb2 + j) * 9 + kk2] : 0.f;
      const ushort h = f2bf(v);
      const float hf = __uint_as_float((uint)h << 16);
      ph[j] = (short)h;
      pl[j] = (short)f2bf(v - hf);
    }
    *(b8*)((short*)(ws + WH) + tid * 8) = ph;
    *(b8*)((short*)(ws + WL) + tid * 8) = pl;
  }
}

// ---------------------------------------------------------------------------
// transpose (XT path): x (B,C,H,W) fp32 -> xt (B,P,C) f16.
// ---------------------------------------------------------------------------
__global__ __launch_bounds__(256) void transpose_k(
    const float* __restrict__ x, float* __restrict__ ws) {
  const int id  = blockIdx.x * 256 + threadIdx.x;   // < 524288
  const int p   = id & 4095;
  const int cg8 = (id >> 12) & 31;
  const int b   = id >> 17;
  const float* xp = x + (((long)(b * 256 + cg8 * 8)) << 12) + p;
  _Float16* xt = (_Float16*)(ws + XT2);
  h8 pk;
#pragma unroll
  for (int j = 0; j < 8; ++j) pk[j] = (_Float16)xp[(long)j << 12];
  *(h8*)(xt + ((((long)(b << 12) + p)) << 8) + (cg8 << 3)) = pk;
}

// ---------------------------------------------------------------------------
// K1 big path: offset conv, K-split x4. Grid 1024 = quarter(4) x b(4) x ho(64).
// Each block: 64 channels (2 cg32 groups), bf16-split MFMA, fp32 atomicAdd
// partials into prep-zeroed OF2. 4 blocks/CU -> latency overlap.
// ---------------------------------------------------------------------------
__global__ __launch_bounds__(256, 4) void offset_part_k(
    const float* __restrict__ x, float* __restrict__ ws) {
  __shared__ __align__(16) ushort Xh[3][66][40];
  __shared__ __align__(16) ushort Xl[3][66][40];
  const int bid = blockIdx.x;
  const int q   = bid >> 8;          // channel quarter 0..3
  const int b   = (bid >> 6) & 3;
  const int ho  = bid & 63;
  const int t   = threadIdx.x;
  const int l   = t & 63;
  const int wv  = t >> 6;
  const short* afh = (const short*)(ws + WH2);
  const short* afl = (const short*)(ws + WL2);

  for (int u = t; u < 240; u += 256) {
    const int row = u / 80, rem = u % 80;
    const int col = (rem >= 40) ? 65 : 0;
    const int c   = rem % 40;
    Xh[row][col][c] = 0;
    Xl[row][col][c] = 0;
  }

  f4 acc[2];
  acc[0] = f4{0.f, 0.f, 0.f, 0.f};
  acc[1] = f4{0.f, 0.f, 0.f, 0.f};

  const int cidx = t >> 3;           // channel within 32-group
  const int j8   = t & 7;
  const float* xc = x + ((long)b << 20) + ((long)cidx << 12);
  const int col = (wv << 4) + (l & 15);
  const int qc  = (l >> 4) << 3;

  for (int it = 0; it < 2; ++it) {
    const int cg = (q << 1) + it;    // absolute cg32 0..7
    __syncthreads();
    const float* xg = xc + ((long)(cg << 5) << 12);
#pragma unroll
    for (int rep = 0; rep < 6; ++rep) {
      const int fi   = (rep << 3) + j8;
      const int row  = fi >> 4;
      const int colf = (fi & 15) << 2;
      const int y = ho - 1 + row;
      f4u v = {0.f, 0.f, 0.f, 0.f};
      if (y >= 0 && y <= 63) v = *(const f4u*)(xg + (y << 6) + colf);
#pragma unroll
      for (int qq = 0; qq < 4; ++qq) {
        const ushort h = f2bf(v[qq]);
        const float hf = __uint_as_float((uint)h << 16);
        Xh[row][colf + 1 + qq][cidx] = h;
        Xl[row][colf + 1 + qq][cidx] = f2bf(v[qq] - hf);
      }
    }
    __syncthreads();
#pragma unroll
    for (int kk = 0; kk < 9; ++kk) {
      const int ky = kk / 3, kx = kk - ky * 3;
      const int i  = cg * 9 + kk;
      const b8 ah0 = *(const b8*)(afh + ((((i << 1) + 0) << 6) + l) * 8);
      const b8 ah1 = *(const b8*)(afh + ((((i << 1) + 1) << 6) + l) * 8);
      const b8 al0 = *(const b8*)(afl + ((((i << 1) + 0) << 6) + l) * 8);
      const b8 al1 = *(const b8*)(afl + ((((i << 1) + 1) << 6) + l) * 8);
      const b8 bh = *(const b8*)&Xh[ky][col + kx][qc];
      const b8 bl = *(const b8*)&Xl[ky][col + kx][qc];
      acc[0] = __builtin_amdgcn_mfma_f32_16x16x32_bf16(ah0, bh, acc[0], 0, 0, 0);
      acc[0] = __builtin_amdgcn_mfma_f32_16x16x32_bf16(ah0, bl, acc[0], 0, 0, 0);
      acc[0] = __builtin_amdgcn_mfma_f32_16x16x32_bf16(al0, bh, acc[0], 0, 0, 0);
      acc[1] = __builtin_amdgcn_mfma_f32_16x16x32_bf16(ah1, bh, acc[1], 0, 0, 0);
      acc[1] = __builtin_amdgcn_mfma_f32_16x16x32_bf16(ah1, bl, acc[1], 0, 0, 0);
      acc[1] = __builtin_amdgcn_mfma_f32_16x16x32_bf16(al1, bh, acc[1], 0, 0, 0);
    }
  }

  const int wo = col;
  const int q4 = (l >> 4) << 2;
#pragma unroll
  for (int mt = 0; mt < 2; ++mt)
#pragma unroll
    for (int r = 0; r < 4; ++r) {
      const int oc = (mt << 4) + q4 + r;
      if (oc < 18)
        atomicAdd(&ws[OF2 + ((b * 18 + oc) << 12) + (ho << 6) + wo],
                  acc[mt][r]);
    }
}

// ---------------------------------------------------------------------------
// K1 fallback: full-channel offset MFMA (R8 verbatim).
// ---------------------------------------------------------------------------
__global__ __launch_bounds__(256) void offset_mfma_k(
    const float* __restrict__ x, float* __restrict__ ws,
    int OFFS, int WH, int WL) {
  __shared__ __align__(16) ushort Xh[3][66][40];
  __shared__ __align__(16) ushort Xl[3][66][40];
  const int bid = blockIdx.x;
  const int b   = bid >> 6;
  const int ho  = bid & 63;
  const int t   = threadIdx.x;
  const int l   = t & 63;
  const int wv  = t >> 6;
  const short* afh = (const short*)(ws + WH);
  const short* afl = (const short*)(ws + WL);

  for (int u = t; u < 240; u += 256) {
    const int row = u / 80, rem = u % 80;
    const int col = (rem >= 40) ? 65 : 0;
    const int c   = rem % 40;
    Xh[row][col][c] = 0;
    Xl[row][col][c] = 0;
  }

  f4 acc[2];
  acc[0] = f4{0.f, 0.f, 0.f, 0.f};
  acc[1] = f4{0.f, 0.f, 0.f, 0.f};

  const int cidx = t >> 3;
  const int j8   = t & 7;
  const float* xc = x + ((long)b << 20) + ((long)cidx << 12);
  const int col = (wv << 4) + (l & 15);
  const int qc  = (l >> 4) << 3;

  for (int cg = 0; cg < 8; ++cg) {
    __syncthreads();
    const float* xg = xc + ((long)(cg << 5) << 12);
#pragma unroll
    for (int rep = 0; rep < 6; ++rep) {
      const int fi   = (rep << 3) + j8;
      const int row  = fi >> 4;
      const int colf = (fi & 15) << 2;
      const int y = ho - 1 + row;
      f4u v = {0.f, 0.f, 0.f, 0.f};
      if (y >= 0 && y <= 63) v = *(const f4u*)(xg + (y << 6) + colf);
#pragma unroll
      for (int qq = 0; qq < 4; ++qq) {
        const ushort h = f2bf(v[qq]);
        const float hf = __uint_as_float((uint)h << 16);
        Xh[row][colf + 1 + qq][cidx] = h;
        Xl[row][colf + 1 + qq][cidx] = f2bf(v[qq] - hf);
      }
    }
    __syncthreads();
#pragma unroll
    for (int kk = 0; kk < 9; ++kk) {
      const int ky = kk / 3, kx = kk - ky * 3;
      const int i  = cg * 9 + kk;
      const b8 ah0 = *(const b8*)(afh + ((((i << 1) + 0) << 6) + l) * 8);
      const b8 ah1 = *(const b8*)(afh + ((((i << 1) + 1) << 6) + l) * 8);
      const b8 al0 = *(const b8*)(afl + ((((i << 1) + 0) << 6) + l) * 8);
      const b8 al1 = *(const b8*)(afl + ((((i << 1) + 1) << 6) + l) * 8);
      const b8 bh = *(const b8*)&Xh[ky][col + kx][qc];
      const b8 bl = *(const b8*)&Xl[ky][col + kx][qc];
      acc[0] = __builtin_amdgcn_mfma_f32_16x16x32_bf16(ah0, bh, acc[0], 0, 0, 0);
      acc[0] = __builtin_amdgcn_mfma_f32_16x16x32_bf16(ah0, bl, acc[0], 0, 0, 0);
      acc[0] = __builtin_amdgcn_mfma_f32_16x16x32_bf16(al0, bh, acc[0], 0, 0, 0);
      acc[1] = __builtin_amdgcn_mfma_f32_16x16x32_bf16(ah1, bh, acc[1], 0, 0, 0);
      acc[1] = __builtin_amdgcn_mfma_f32_16x16x32_bf16(ah1, bl, acc[1], 0, 0, 0);
      acc[1] = __builtin_amdgcn_mfma_f32_16x16x32_bf16(al1, bh, acc[1], 0, 0, 0);
    }
  }

  const int wo = col;
  const int q4 = (l >> 4) << 2;
#pragma unroll
  for (int mt = 0; mt < 2; ++mt)
#pragma unroll
    for (int r = 0; r < 4; ++r) {
      const int oc = (mt << 4) + q4 + r;
      if (oc < 18)
        ws[OFFS + ((b * 18 + oc) << 12) + (ho << 6) + wo] = acc[mt][r];
    }
}

// ---------------------------------------------------------------------------
// descriptor math (shared inline)
// ---------------------------------------------------------------------------
struct DescOut {
  float w00, w01, w10, w11;
  int y0c, y1c, x0c, x1c;
};
__device__ inline DescOut desc_math(const float* ws, const float* bof,
                                    int OFFS, int d) {
  const int k  = d >> 14;
  const int n  = d & 16383;
  const int b  = n >> 12;
  const int sp = n & 4095;
  const int ho = sp >> 6, wo = sp & 63;
  const int ky = k / 3, kx = k - ky * 3;
  const float dy = ws[OFFS + ((b * 18 + (k << 1)) << 12) + sp] + bof[k << 1];
  const float dx = ws[OFFS + ((b * 18 + (k << 1) + 1) << 12) + sp] + bof[(k << 1) + 1];
  const float py = (float)(ho - 1 + ky) + dy;
  const float px = (float)(wo - 1 + kx) + dx;
  const float y0f = floorf(py), x0f = floorf(px);
  const float ly = py - y0f, lx = px - x0f;
  const int y0 = (int)y0f, x0 = (int)x0f;
  const int y1 = y0 + 1, x1 = x0 + 1;
  const float vy0 = (y0 >= 0 && y0 < 64) ? 1.f : 0.f;
  const float vy1 = (y1 >= 0 && y1 < 64) ? 1.f : 0.f;
  const float vx0 = (x0 >= 0 && x0 < 64) ? 1.f : 0.f;
  const float vx1 = (x1 >= 0 && x1 < 64) ? 1.f : 0.f;
  DescOut o;
  o.y0c = min(max(y0, 0), 63); o.y1c = min(max(y1, 0), 63);
  o.x0c = min(max(x0, 0), 63); o.x1c = min(max(x1, 0), 63);
  o.w00 = (1.f - ly) * (1.f - lx) * vy0 * vx0;
  o.w01 = (1.f - ly) * lx * vy0 * vx1;
  o.w10 = ly * (1.f - lx) * vy1 * vx0;
  o.w11 = ly * lx * vy1 * vx1;
  return o;
}

// ---------------------------------------------------------------------------
// K2 fallback (R7 quad-descriptor form)
// ---------------------------------------------------------------------------
__global__ __launch_bounds__(256) void make_desc_k(
    const float* __restrict__ bof, float* __restrict__ ws) {
  const int d = blockIdx.x * 256 + threadIdx.x;
  DescOut q = desc_math(ws, bof, WS_OFFS, d);
  const int xf = min(q.x0c & ~1, 60);
  f4 g0 = {0.f, 0.f, 0.f, 0.f}, g1 = {0.f, 0.f, 0.f, 0.f};
#pragma unroll
  for (int j = 0; j < 4; ++j) {
    const int col = xf + j;
    g0[j] = (col == q.x0c ? q.w00 : 0.f) + (col == q.x1c ? q.w01 : 0.f);
    g1[j] = (col == q.x0c ? q.w10 : 0.f) + (col == q.x1c ? q.w11 : 0.f);
  }
  ((f4*)(ws + WS_GY0))[d] = g0;
  ((f4*)(ws + WS_GY1))[d] = g1;
  int2 ip; ip.x = (q.y0c << 6) + xf; ip.y = (q.y1c << 6) + xf;
  ((int2*)(ws + WS_IP))[d] = ip;
}

// ---------------------------------------------------------------------------
// K2 XT: half2-dup weights (uint4) + 4 corner positions (int4)
// ---------------------------------------------------------------------------
__global__ __launch_bounds__(256) void make_desc_xt(
    const float* __restrict__ bof, float* __restrict__ ws) {
  const int d = blockIdx.x * 256 + threadIdx.x;
  DescOut q = desc_math(ws, bof, OF2, d);
  uint4 wv;
  wv.x = duph(q.w00); wv.y = duph(q.w01);
  wv.z = duph(q.w10); wv.w = duph(q.w11);
  int4 pv;
  pv.x = (q.y0c << 6) + q.x0c;
  pv.y = (q.y0c << 6) + q.x1c;
  pv.z = (q.y1c << 6) + q.x0c;
  pv.w = (q.y1c << 6) + q.x1c;
  ((uint4*)(ws + DW2))[d] = wv;
  ((int4*)(ws + DP2))[d] = pv;
}

// ---------------------------------------------------------------------------
// K3 fallback: R7 gemm verbatim
// ---------------------------------------------------------------------------
__global__ __launch_bounds__(512, 4) void deform_gemm_k(
    const float* __restrict__ x, const float* __restrict__ ws,
    float* __restrict__ out) {
  __shared__ ushort Bsf[2][32][40];
  __shared__ f4   dG0[288];
  __shared__ f4   dG1[288];
  __shared__ int2 dIP[288];

  const int t     = threadIdx.x;
  const int bid   = blockIdx.x;
  const int xcd   = bid & 7;
  const int batch = xcd >> 1;
  const int j     = bid >> 3;
  const int sp0   = ((((xcd & 1) << 6) + j) << 5);
  const int nd0   = (batch << 12) + sp0;
  const int l     = t & 63;
  const int wv    = t >> 6;

  const int sn = t & 31;
  const int cs = t >> 5;
  const float* xb = x + ((long)batch << 20);
  const short* af = (const short*)(ws + WS_AFRAG);

  if (t < 288) {
    const int kk = t >> 5, s = t & 31;
    const int dg = (kk << 14) + nd0 + s;
    dG0[t] = ((const f4*)(ws + WS_GY0))[dg];
    dG1[t] = ((const f4*)(ws + WS_GY1))[dg];
    dIP[t] = ((const int2*)(ws + WS_IP))[dg];
  }
  __syncthreads();

  f4 acc[2][2];
#pragma unroll
  for (int i = 0; i < 2; ++i)
#pragma unroll
    for (int q = 0; q < 2; ++q) acc[i][q] = f4{0.f, 0.f, 0.f, 0.f};

  const int otb = wv << 1;
  b8 aA[2], aN[2];
  f4 g0, g1; int p0, p1;
  f4u r00, r01, r10, r11;

#define RDDESC(KK_) do { const int u_ = ((KK_) << 5) + sn;                   \
    g0 = dG0[u_]; g1 = dG1[u_];                                              \
    const int2 ip_ = dIP[u_]; p0 = ip_.x; p1 = ip_.y; } while (0)

#define GATHER(CG_) do {                                                     \
    const int c0_ = ((CG_) << 5) + (cs << 1);                                \
    const float* pl0_ = xb + ((long)c0_ << 12);                              \
    const float* pl1_ = pl0_ + 4096;                                         \
    r00 = *(const f4u*)(pl0_ + p0);  r01 = *(const f4u*)(pl0_ + p1);         \
    r10 = *(const f4u*)(pl1_ + p0);  r11 = *(const f4u*)(pl1_ + p1);         \
  } while (0)

#define COMBINE(BUF_) do {                                                   \
    const float v0_ = g0.x * r00.x + g0.y * r00.y + g0.z * r00.z +           \
                      g0.w * r00.w + g1.x * r01.x + g1.y * r01.y +           \
                      g1.z * r01.z + g1.w * r01.w;                           \
    const float v1_ = g0.x * r10.x + g0.y * r10.y + g0.z * r10.z +           \
                      g0.w * r10.w + g1.x * r11.x + g1.y * r11.y +           \
                      g1.z * r11.z + g1.w * r11.w;                           \
    ushort2 pk_; pk_.x = f2bf(v0_); pk_.y = f2bf(v1_);                       \
    *(ushort2*)&Bsf[BUF_][sn][cs << 1] = pk_; } while (0)

#define LOADA(I_, DST_) do {                                                 \
    _Pragma("unroll")                                                        \
    for (int m = 0; m < 2; ++m)                                              \
      DST_[m] = *(const b8*)(af + (((((I_) << 4) + otb + m) << 6) + l) * 8); \
  } while (0)

  RDDESC(0);
  GATHER(0);
  LOADA(0, aA);
  COMBINE(0);
  RDDESC(1);
  __syncthreads();

  int kkN = 1, cgN = 0;
  for (int i = 0; i < 72; ++i) {
    const int cur = i & 1;
    if (i < 71) {
      GATHER(cgN);
      LOADA(i + 1, aN);
    }
    b8 bB[2];
#pragma unroll
    for (int nt = 0; nt < 2; ++nt)
      bB[nt] = *(const b8*)&Bsf[cur][(nt << 4) + (l & 15)][(l >> 4) << 3];
#pragma unroll
    for (int mt = 0; mt < 2; ++mt)
#pragma unroll
      for (int nt = 0; nt < 2; ++nt)
        acc[mt][nt] = __builtin_amdgcn_mfma_f32_16x16x32_bf16(
            aA[mt], bB[nt], acc[mt][nt], 0, 0, 0);
    if (i < 71) {
      COMBINE(cur ^ 1);
      kkN++; if (kkN == 9) { kkN = 0; cgN++; }
      if (i < 70) RDDESC(kkN);
#pragma unroll
      for (int m = 0; m < 2; ++m) aA[m] = aN[m];
    }
    __syncthreads();
  }
#undef RDDESC
#undef GATHER
#undef COMBINE
#undef LOADA

  const float* bfold = ws + WS_BFOLD;
  const int q4 = (l >> 4) << 2;
  const int ow = wv << 5;
#pragma unroll
  for (int mt = 0; mt < 2; ++mt) {
    const int ob = ow + (mt << 4) + q4;
    const f4 bf = *(const f4*)&bfold[ob];
#pragma unroll
    for (int nt = 0; nt < 2; ++nt) {
      const int sp = sp0 + (nt << 4) + (l & 15);
#pragma unroll
      for (int r = 0; r < 4; ++r) {
        const int o = ob + r;
        out[(((batch << 8) + o) << 12) + sp] =
            fmaxf(acc[mt][nt][r] + bf[r], 0.f);
      }
    }
  }
}

// ---------------------------------------------------------------------------
// K3 big path: f16 MFMA GEMM, triple-buffered pipelined deformable im2col.
// Grid 256 x 512 thr (8 waves). Tile 256o x 64n; wave = 64o x 32n. BK=64:
// 36 iters (cw64-outer, kk-inner). Gather iter i+2 at top of iter i, pk_fma
// combine at bottom of iter i+1 (~1.2 iter load->use distance). XOR-swizzled
// Bs (chunk ^= sn&7), no padding. Parity-unrolled (no reg copies).
// ---------------------------------------------------------------------------
__global__ __launch_bounds__(512, 2) void deform_gemm_f16(
    const float* __restrict__ ws, float* __restrict__ out) {
  __shared__ __align__(16) uint Bs[3][64][32];   // 24 KB f16 tiles
  __shared__ uint4 dW[576];                      // 9 KB
  __shared__ int4  dP[576];                      // 9 KB

  const int t     = threadIdx.x;
  const int bid   = blockIdx.x;
  const int xcd   = bid & 7;
  const int batch = xcd >> 1;
  const int half  = xcd & 1;
  const int slot  = bid >> 3;                    // 0..31
  const int sp0   = (half << 11) + (slot << 6);
  const int nd0   = (batch << 12) + sp0;
  const int l     = t & 63;
  const int wv    = t >> 6;                      // 0..7

  const int sn  = t & 63;             // sample column
  const int cg8 = t >> 6;             // 8-ch slice within 64-ch window
  const uint* xtu = (const uint*)(ws + XT2) + ((long)batch << 19);
  const _Float16* af = (const _Float16*)(ws + AF2);

  // fill descriptor LDS: 576 = 9 kk x 64 samples
  for (int u = t; u < 576; u += 512) {
    const int kk = u >> 6, s = u & 63;
    const int dg = (kk << 14) + nd0 + s;
    dW[u] = ((const uint4*)(ws + DW2))[dg];
    dP[u] = ((const int4*)(ws + DP2))[dg];
  }
  __syncthreads();

  f4 acc[4][2];
#pragma unroll
  for (int m = 0; m < 4; ++m)
#pragma unroll
    for (int nt = 0; nt < 2; ++nt) acc[m][nt] = f4{0.f, 0.f, 0.f, 0.f};

  uint4 cset0[4], cset1[4];           // two outstanding corner sets
  uint4 w0v, w1v, wq; int4 pq;
  h8 aA[4][2], aN[4][2];
  int kkd, kkg, cwg, bufc;

#define FRDD(W_, P_, KK_) do { const int u_ = ((KK_) << 6) + sn;             \
    W_ = dW[u_]; P_ = dP[u_]; } while (0)

#define FGATH(DST_, P_) do {                                                 \
    const int co_ = (cwg << 5) + (cg8 << 2);                                 \
    DST_[0] = *(const uint4*)(xtu + ((P_).x << 7) + co_);                    \
    DST_[1] = *(const uint4*)(xtu + ((P_).y << 7) + co_);                    \
    DST_[2] = *(const uint4*)(xtu + ((P_).z << 7) + co_);                    \
    DST_[3] = *(const uint4*)(xtu + ((P_).w << 7) + co_);                    \
  } while (0)

#define FCOMB(CS_, WV_, BUF_) do {                                           \
    const h2 wc0_ = u2h2((WV_).x), wc1_ = u2h2((WV_).y);                     \
    const h2 wc2_ = u2h2((WV_).z), wc3_ = u2h2((WV_).w);                     \
    uint4 r_;                                                                \
    r_.x = h22u(u2h2(CS_[0].x) * wc0_ + u2h2(CS_[1].x) * wc1_ +              \
                u2h2(CS_[2].x) * wc2_ + u2h2(CS_[3].x) * wc3_);              \
    r_.y = h22u(u2h2(CS_[0].y) * wc0_ + u2h2(CS_[1].y) * wc1_ +              \
                u2h2(CS_[2].y) * wc2_ + u2h2(CS_[3].y) * wc3_);              \
    r_.z = h22u(u2h2(CS_[0].z) * wc0_ + u2h2(CS_[1].z) * wc1_ +              \
                u2h2(CS_[2].z) * wc2_ + u2h2(CS_[3].z) * wc3_);              \
    r_.w = h22u(u2h2(CS_[0].w) * wc0_ + u2h2(CS_[1].w) * wc1_ +              \
                u2h2(CS_[2].w) * wc2_ + u2h2(CS_[3].w) * wc3_);              \
    *(uint4*)&Bs[BUF_][sn][(cg8 ^ (sn & 7)) << 2] = r_;                      \
  } while (0)

#define FLOADA(I_, DST_) do {                                                \
    _Pragma("unroll")                                                        \
    for (int m = 0; m < 4; ++m)                                              \
      _Pragma("unroll")                                                      \
      for (int s = 0; s < 2; ++s) {                                          \
        const int f_ = ((I_) << 1) + s;                                      \
        DST_[m][s] = *(const h8*)(af +                                       \
            ((((f_ << 4) + ((wv >> 1) << 2) + m) << 6) + l) * 8);            \
      }                                                                      \
  } while (0)

#define FMFMA(AC_, BUF_) do {                                                \
    h8 bB_[2][2];                                                            \
    _Pragma("unroll")                                                        \
    for (int nt = 0; nt < 2; ++nt)                                           \
      _Pragma("unroll")                                                      \
      for (int s = 0; s < 2; ++s) {                                          \
        const int snr_ = ((wv & 1) << 5) + (nt << 4) + (l & 15);             \
        const int ph_  = (((s << 2) + (l >> 4)) ^ (snr_ & 7)) << 2;          \
        bB_[nt][s] = *(const h8*)&Bs[BUF_][snr_][ph_];                       \
      }                                                                      \
    _Pragma("unroll")                                                        \
    for (int m = 0; m < 4; ++m)                                              \
      _Pragma("unroll")                                                      \
      for (int nt = 0; nt < 2; ++nt) {                                       \
        acc[m][nt] = __builtin_amdgcn_mfma_f32_16x16x32_f16(                 \
            AC_[m][0], bB_[nt][0], acc[m][nt], 0, 0, 0);                     \
        acc[m][nt] = __builtin_amdgcn_mfma_f32_16x16x32_f16(                 \
            AC_[m][1], bB_[nt][1], acc[m][nt], 0, 0, 0);                     \
      }                                                                      \
  } while (0)

#define FBODY(I_, AC_, AN_, CC_, WC_, CN_, WN_) do {                         \
    if ((I_) < 34) {                                                         \
      WN_ = wq; FGATH(CN_, pq);                                              \
      kkg++; if (kkg == 9) { kkg = 0; cwg++; }                               \
    }                                                                        \
    if ((I_) < 33) { FRDD(wq, pq, kkd); kkd = (kkd == 8) ? 0 : kkd + 1; }    \
    const int bufn_ = (bufc == 2) ? 0 : bufc + 1;                            \
    FMFMA(AC_, bufc);                                                        \
    if ((I_) < 35) {                                                         \
      FLOADA((I_) + 1, AN_);                                                 \
      FCOMB(CC_, WC_, bufn_);                                                \
    }                                                                        \
    bufc = bufn_;                                                            \
    __syncthreads();                                                         \
  } while (0)

  // ---- prologue: gather iters 0 and 1 (cw=0), desc queue = iter 2 ----
  {
    uint4 wA; int4 pA;
    cwg = 0;
    FRDD(wA, pA, 0);
    FGATH(cset0, pA);
    FRDD(w1v, pA, 1);
    FGATH(cset1, pA);
    FRDD(wq, pq, 2);
    FLOADA(0, aA);
    FCOMB(cset0, wA, 0);
    kkd = 3; kkg = 2; bufc = 0;
  }
  __syncthreads();

  for (int i = 0; i < 36; i += 2) {
    FBODY(i,     aA, aN, cset1, w1v, cset0, w0v);
    FBODY(i + 1, aN, aA, cset0, w0v, cset1, w1v);
  }

  const float* bfold = ws + BF2;
  const int quad = l >> 4;
  const int ow = (wv >> 1) << 6;
  const int nw = (wv & 1) << 5;
#pragma unroll
  for (int m = 0; m < 4; ++m) {
    const int ob = ow + (m << 4) + (quad << 2);
    const f4 bf = *(const f4*)&bfold[ob];
#pragma unroll
    for (int nt = 0; nt < 2; ++nt) {
      const int sp = sp0 + nw + (nt << 4) + (l & 15);
#pragma unroll
      for (int r = 0; r < 4; ++r) {
        out[(((batch << 8) + ob + r) << 12) + sp] =
            fmaxf(acc[m][nt][r] + bf[r], 0.f);
      }
    }
  }
}

// ---------------------------------------------------------------------------
extern "C" void kernel_launch(void* const* d_in, const int* in_sizes, int n_in,
                              void* d_out, int out_size, void* d_ws, size_t ws_size,
                              hipStream_t stream) {
  const float* x     = (const float*)d_in[0];
  const float* wof   = (const float*)d_in[1];
  const float* bof   = (const float*)d_in[2];
  const float* w     = (const float*)d_in[3];
  const float* bias  = (const float*)d_in[4];
  const float* gamma = (const float*)d_in[5];
  const float* beta  = (const float*)d_in[6];
  const float* mean  = (const float*)d_in[7];
  const float* var   = (const float*)d_in[8];
  float* out = (float*)d_out;
  float* ws  = (float*)d_ws;

  const bool big = ws_size >= (size_t)XT_TOTAL_BYTES;
  if (big) {
    hipLaunchKernelGGL(prep_k, dim3(288), dim3(256), 0, stream,
                       w, wof, bias, gamma, beta, mean, var, ws,
                       AF2, BF2, WH2, WL2, 1);
    hipLaunchKernelGGL(transpose_k, dim3(2048), dim3(256), 0, stream, x, ws);
    hipLaunchKernelGGL(offset_part_k, dim3(1024), dim3(256), 0, stream, x, ws);
    hipLaunchKernelGGL(make_desc_xt, dim3(576), dim3(256), 0, stream, bof, ws);
    hipLaunchKernelGGL(deform_gemm_f16, dim3(256), dim3(512), 0, stream,
                       ws, out);
  } else {
    hipLaunchKernelGGL(prep_k, dim3(288), dim3(256), 0, stream,
                       w, wof, bias, gamma, beta, mean, var, ws,
                       WS_AFRAG, WS_BFOLD, WS_K1WH, WS_K1WL, 0);
    hipLaunchKernelGGL(offset_mfma_k, dim3(256), dim3(256), 0, stream,
                       x, ws, WS_OFFS, WS_K1WH, WS_K1WL);
    hipLaunchKernelGGL(make_desc_k, dim3(576), dim3(256), 0, stream, bof, ws);
    hipLaunchKernelGGL(deform_gemm_k, dim3(512), dim3(512), 0, stream,
                       x, ws, out);
  }
}

// Round 10
// 162.793 us; speedup vs baseline: 1.9815x; 1.0011x over previous
//
#include <hip/hip_runtime.h>
#include <math.h>

typedef __attribute__((ext_vector_type(8))) short b8;
typedef __attribute__((ext_vector_type(4))) short s4;
typedef __attribute__((ext_vector_type(4))) float f4;
typedef __attribute__((ext_vector_type(4))) int i4;
typedef float f4u __attribute__((ext_vector_type(4), aligned(4)));  // align-4 float4
typedef _Float16 h8 __attribute__((ext_vector_type(8)));
typedef _Float16 h2 __attribute__((ext_vector_type(2)));

// ---------------- fallback (R7) ws layout (float offsets) ------------------
#define WS_OFFS   0                 // 294912 (B*18*HW)
#define WS_GY0    294912            // float4[147456]
#define WS_GY1    884736
#define WS_IP     1474560           // int2[147456]
#define WS_AFRAG  1769472           // bf16[589824]
#define WS_BFOLD  2064384
#define WS_K1WH   294912            // overlay in GY0 (prep->K1, then K2 overwrites)
#define WS_K1WL   331776
// fallback total 2064640 floats = 8,258,560 B (known-good)

// ---------------- big-ws (XT) layout (float offsets) -----------------------
#define XT2   0                     // f16[4*4096*256] = 2097152 floats
#define OF2   2097152               // 294912 (fp32 accumulated offsets)
#define DW2   2392064               // uint4[147456] = 589824 floats (half2-dup weights)
#define DP2   2981888               // int4[147456] = 589824 floats (corner positions)
#define AF2   3571712               // f16[589824] = 294912 floats
#define BF2   3866624               // 256
#define WH2   2392064               // overlay in DW2 (prep->offset, desc overwrites)
#define WL2   2428928
#define XT_TOTAL_BYTES (3866880u * 4u)   // 15,467,520

__device__ inline ushort f2bf(float f) {
  uint u = __float_as_uint(f);
  return (ushort)((u + 0x7FFFu + ((u >> 16) & 1u)) >> 16);   // RNE
}
__device__ inline float bf2f(short s) {
  return __uint_as_float(((uint)(ushort)s) << 16);
}
__device__ inline h2 u2h2(uint u) { union { uint u; h2 h; } x; x.u = u; return x.h; }
__device__ inline uint h22u(h2 h) { union { uint u; h2 h; } x; x.h = h; return x.u; }
__device__ inline uint duph(float f) {
  union { _Float16 h; ushort u; } x; x.h = (_Float16)f;
  return ((uint)x.u << 16) | x.u;
}

// ---------------------------------------------------------------------------
// prep: (a) main A-frags (weight*BN) in iteration order — mode 0: bf16, old
// (cg32,kk) order; mode 1: f16, (cw64,kk,s) order + zero the OF2 accumulator;
// (b) folded bias; (c) K1 offset-conv A-frags, bf16 split, M padded 18->32.
// ---------------------------------------------------------------------------
__global__ __launch_bounds__(256) void prep_k(
    const float* __restrict__ w, const float* __restrict__ wof,
    const float* __restrict__ bias,
    const float* __restrict__ gamma, const float* __restrict__ beta,
    const float* __restrict__ mean, const float* __restrict__ var,
    float* __restrict__ ws, int AF, int BF, int WH, int WL, int mode) {
  const int tid = blockIdx.x * 256 + threadIdx.x;    // < 73728
  const int l  = tid & 63;
  const int ot = (tid >> 6) & 15;
  const int f  = tid >> 10;          // 0..71
  const int o  = (ot << 4) + (l & 15);
  const float inv = gamma[o] * rsqrtf(var[o] + 1e-5f);
  if (mode == 0) {
    const int cg = f / 9;
    const int kk = f - cg * 9;
    const int cb = (cg << 5) + ((l >> 4) << 3);
    b8 pk;
#pragma unroll
    for (int j = 0; j < 8; ++j)
      pk[j] = (short)f2bf(w[((o << 8) + cb + j) * 9 + kk] * inv);
    *(b8*)((short*)(ws + AF) + tid * 8) = pk;
  } else {
    const int s  = f & 1;
    const int g  = f >> 1;           // 0..35
    const int cw = g / 9;
    const int kk = g - cw * 9;
    const int cb = (cw << 6) + (s << 5) + ((l >> 4) << 3);
    h8 pk;
#pragma unroll
    for (int j = 0; j < 8; ++j)
      pk[j] = (_Float16)(w[((o << 8) + cb + j) * 9 + kk] * inv);
    *(h8*)((_Float16*)(ws + AF) + tid * 8) = pk;
    // zero the offset accumulator (294912 floats = 73728 f4)
    ((f4*)(ws + OF2))[tid] = f4{0.f, 0.f, 0.f, 0.f};
  }
  if (tid < 256) {
    const float iv = gamma[tid] * rsqrtf(var[tid] + 1e-5f);
    ws[BF + tid] = bias[tid] * iv + beta[tid] - mean[tid] * iv;
  }
  if (tid < 9216) {
    const int l2  = tid & 63;
    const int mt  = (tid >> 6) & 1;
    const int i2  = tid >> 7;        // 0..71
    const int cg2 = i2 / 9;
    const int kk2 = i2 - cg2 * 9;
    const int oc  = (mt << 4) + (l2 & 15);
    const int cb2 = (cg2 << 5) + ((l2 >> 4) << 3);
    b8 ph, pl;
#pragma unroll
    for (int j = 0; j < 8; ++j) {
      const float v = (oc < 18) ? wof[((oc << 8) + cb2 + j) * 9 + kk2] : 0.f;
      const ushort h = f2bf(v);
      const float hf = __uint_as_float((uint)h << 16);
      ph[j] = (short)h;
      pl[j] = (short)f2bf(v - hf);
    }
    *(b8*)((short*)(ws + WH) + tid * 8) = ph;
    *(b8*)((short*)(ws + WL) + tid * 8) = pl;
  }
}

// ---------------------------------------------------------------------------
// transpose (XT path): x (B,C,H,W) fp32 -> xt (B,P,C) f16.
// ---------------------------------------------------------------------------
__global__ __launch_bounds__(256) void transpose_k(
    const float* __restrict__ x, float* __restrict__ ws) {
  const int id  = blockIdx.x * 256 + threadIdx.x;   // < 524288
  const int p   = id & 4095;
  const int cg8 = (id >> 12) & 31;
  const int b   = id >> 17;
  const float* xp = x + (((long)(b * 256 + cg8 * 8)) << 12) + p;
  _Float16* xt = (_Float16*)(ws + XT2);
  h8 pk;
#pragma unroll
  for (int j = 0; j < 8; ++j) pk[j] = (_Float16)xp[(long)j << 12];
  *(h8*)(xt + ((((long)(b << 12) + p)) << 8) + (cg8 << 3)) = pk;
}

// ---------------------------------------------------------------------------
// K1 big path: offset conv, K-split x4. Grid 1024 = quarter(4) x b(4) x ho(64).
// Each block: 64 channels (2 cg32 groups), bf16-split MFMA, fp32 atomicAdd
// partials into prep-zeroed OF2. 4 blocks/CU -> latency overlap.
// ---------------------------------------------------------------------------
__global__ __launch_bounds__(256, 4) void offset_part_k(
    const float* __restrict__ x, float* __restrict__ ws) {
  __shared__ __align__(16) ushort Xh[3][66][40];
  __shared__ __align__(16) ushort Xl[3][66][40];
  const int bid = blockIdx.x;
  const int q   = bid >> 8;          // channel quarter 0..3
  const int b   = (bid >> 6) & 3;
  const int ho  = bid & 63;
  const int t   = threadIdx.x;
  const int l   = t & 63;
  const int wv  = t >> 6;
  const short* afh = (const short*)(ws + WH2);
  const short* afl = (const short*)(ws + WL2);

  for (int u = t; u < 240; u += 256) {
    const int row = u / 80, rem = u % 80;
    const int col = (rem >= 40) ? 65 : 0;
    const int c   = rem % 40;
    Xh[row][col][c] = 0;
    Xl[row][col][c] = 0;
  }

  f4 acc[2];
  acc[0] = f4{0.f, 0.f, 0.f, 0.f};
  acc[1] = f4{0.f, 0.f, 0.f, 0.f};

  const int cidx = t >> 3;           // channel within 32-group
  const int j8   = t & 7;
  const float* xc = x + ((long)b << 20) + ((long)cidx << 12);
  const int col = (wv << 4) + (l & 15);
  const int qc  = (l >> 4) << 3;

  for (int it = 0; it < 2; ++it) {
    const int cg = (q << 1) + it;    // absolute cg32 0..7
    __syncthreads();
    const float* xg = xc + ((long)(cg << 5) << 12);
#pragma unroll
    for (int rep = 0; rep < 6; ++rep) {
      const int fi   = (rep << 3) + j8;
      const int row  = fi >> 4;
      const int colf = (fi & 15) << 2;
      const int y = ho - 1 + row;
      f4u v = {0.f, 0.f, 0.f, 0.f};
      if (y >= 0 && y <= 63) v = *(const f4u*)(xg + (y << 6) + colf);
#pragma unroll
      for (int qq = 0; qq < 4; ++qq) {
        const ushort h = f2bf(v[qq]);
        const float hf = __uint_as_float((uint)h << 16);
        Xh[row][colf + 1 + qq][cidx] = h;
        Xl[row][colf + 1 + qq][cidx] = f2bf(v[qq] - hf);
      }
    }
    __syncthreads();
#pragma unroll
    for (int kk = 0; kk < 9; ++kk) {
      const int ky = kk / 3, kx = kk - ky * 3;
      const int i  = cg * 9 + kk;
      const b8 ah0 = *(const b8*)(afh + ((((i << 1) + 0) << 6) + l) * 8);
      const b8 ah1 = *(const b8*)(afh + ((((i << 1) + 1) << 6) + l) * 8);
      const b8 al0 = *(const b8*)(afl + ((((i << 1) + 0) << 6) + l) * 8);
      const b8 al1 = *(const b8*)(afl + ((((i << 1) + 1) << 6) + l) * 8);
      const b8 bh = *(const b8*)&Xh[ky][col + kx][qc];
      const b8 bl = *(const b8*)&Xl[ky][col + kx][qc];
      acc[0] = __builtin_amdgcn_mfma_f32_16x16x32_bf16(ah0, bh, acc[0], 0, 0, 0);
      acc[0] = __builtin_amdgcn_mfma_f32_16x16x32_bf16(ah0, bl, acc[0], 0, 0, 0);
      acc[0] = __builtin_amdgcn_mfma_f32_16x16x32_bf16(al0, bh, acc[0], 0, 0, 0);
      acc[1] = __builtin_amdgcn_mfma_f32_16x16x32_bf16(ah1, bh, acc[1], 0, 0, 0);
      acc[1] = __builtin_amdgcn_mfma_f32_16x16x32_bf16(ah1, bl, acc[1], 0, 0, 0);
      acc[1] = __builtin_amdgcn_mfma_f32_16x16x32_bf16(al1, bh, acc[1], 0, 0, 0);
    }
  }

  const int wo = col;
  const int q4 = (l >> 4) << 2;
#pragma unroll
  for (int mt = 0; mt < 2; ++mt)
#pragma unroll
    for (int r = 0; r < 4; ++r) {
      const int oc = (mt << 4) + q4 + r;
      if (oc < 18)
        atomicAdd(&ws[OF2 + ((b * 18 + oc) << 12) + (ho << 6) + wo],
                  acc[mt][r]);
    }
}

// ---------------------------------------------------------------------------
// K1 fallback: full-channel offset MFMA (R8 verbatim).
// ---------------------------------------------------------------------------
__global__ __launch_bounds__(256) void offset_mfma_k(
    const float* __restrict__ x, float* __restrict__ ws,
    int OFFS, int WH, int WL) {
  __shared__ __align__(16) ushort Xh[3][66][40];
  __shared__ __align__(16) ushort Xl[3][66][40];
  const int bid = blockIdx.x;
  const int b   = bid >> 6;
  const int ho  = bid & 63;
  const int t   = threadIdx.x;
  const int l   = t & 63;
  const int wv  = t >> 6;
  const short* afh = (const short*)(ws + WH);
  const short* afl = (const short*)(ws + WL);

  for (int u = t; u < 240; u += 256) {
    const int row = u / 80, rem = u % 80;
    const int col = (rem >= 40) ? 65 : 0;
    const int c   = rem % 40;
    Xh[row][col][c] = 0;
    Xl[row][col][c] = 0;
  }

  f4 acc[2];
  acc[0] = f4{0.f, 0.f, 0.f, 0.f};
  acc[1] = f4{0.f, 0.f, 0.f, 0.f};

  const int cidx = t >> 3;
  const int j8   = t & 7;
  const float* xc = x + ((long)b << 20) + ((long)cidx << 12);
  const int col = (wv << 4) + (l & 15);
  const int qc  = (l >> 4) << 3;

  for (int cg = 0; cg < 8; ++cg) {
    __syncthreads();
    const float* xg = xc + ((long)(cg << 5) << 12);
#pragma unroll
    for (int rep = 0; rep < 6; ++rep) {
      const int fi   = (rep << 3) + j8;
      const int row  = fi >> 4;
      const int colf = (fi & 15) << 2;
      const int y = ho - 1 + row;
      f4u v = {0.f, 0.f, 0.f, 0.f};
      if (y >= 0 && y <= 63) v = *(const f4u*)(xg + (y << 6) + colf);
#pragma unroll
      for (int qq = 0; qq < 4; ++qq) {
        const ushort h = f2bf(v[qq]);
        const float hf = __uint_as_float((uint)h << 16);
        Xh[row][colf + 1 + qq][cidx] = h;
        Xl[row][colf + 1 + qq][cidx] = f2bf(v[qq] - hf);
      }
    }
    __syncthreads();
#pragma unroll
    for (int kk = 0; kk < 9; ++kk) {
      const int ky = kk / 3, kx = kk - ky * 3;
      const int i  = cg * 9 + kk;
      const b8 ah0 = *(const b8*)(afh + ((((i << 1) + 0) << 6) + l) * 8);
      const b8 ah1 = *(const b8*)(afh + ((((i << 1) + 1) << 6) + l) * 8);
      const b8 al0 = *(const b8*)(afl + ((((i << 1) + 0) << 6) + l) * 8);
      const b8 al1 = *(const b8*)(afl + ((((i << 1) + 1) << 6) + l) * 8);
      const b8 bh = *(const b8*)&Xh[ky][col + kx][qc];
      const b8 bl = *(const b8*)&Xl[ky][col + kx][qc];
      acc[0] = __builtin_amdgcn_mfma_f32_16x16x32_bf16(ah0, bh, acc[0], 0, 0, 0);
      acc[0] = __builtin_amdgcn_mfma_f32_16x16x32_bf16(ah0, bl, acc[0], 0, 0, 0);
      acc[0] = __builtin_amdgcn_mfma_f32_16x16x32_bf16(al0, bh, acc[0], 0, 0, 0);
      acc[1] = __builtin_amdgcn_mfma_f32_16x16x32_bf16(ah1, bh, acc[1], 0, 0, 0);
      acc[1] = __builtin_amdgcn_mfma_f32_16x16x32_bf16(ah1, bl, acc[1], 0, 0, 0);
      acc[1] = __builtin_amdgcn_mfma_f32_16x16x32_bf16(al1, bh, acc[1], 0, 0, 0);
    }
  }

  const int wo = col;
  const int q4 = (l >> 4) << 2;
#pragma unroll
  for (int mt = 0; mt < 2; ++mt)
#pragma unroll
    for (int r = 0; r < 4; ++r) {
      const int oc = (mt << 4) + q4 + r;
      if (oc < 18)
        ws[OFFS + ((b * 18 + oc) << 12) + (ho << 6) + wo] = acc[mt][r];
    }
}

// ---------------------------------------------------------------------------
// descriptor math (shared inline)
// ---------------------------------------------------------------------------
struct DescOut {
  float w00, w01, w10, w11;
  int y0c, y1c, x0c, x1c;
};
__device__ inline DescOut desc_math(const float* ws, const float* bof,
                                    int OFFS, int d) {
  const int k  = d >> 14;
  const int n  = d & 16383;
  const int b  = n >> 12;
  const int sp = n & 4095;
  const int ho = sp >> 6, wo = sp & 63;
  const int ky = k / 3, kx = k - ky * 3;
  const float dy = ws[OFFS + ((b * 18 + (k << 1)) << 12) + sp] + bof[k << 1];
  const float dx = ws[OFFS + ((b * 18 + (k << 1) + 1) << 12) + sp] + bof[(k << 1) + 1];
  const float py = (float)(ho - 1 + ky) + dy;
  const float px = (float)(wo - 1 + kx) + dx;
  const float y0f = floorf(py), x0f = floorf(px);
  const float ly = py - y0f, lx = px - x0f;
  const int y0 = (int)y0f, x0 = (int)x0f;
  const int y1 = y0 + 1, x1 = x0 + 1;
  const float vy0 = (y0 >= 0 && y0 < 64) ? 1.f : 0.f;
  const float vy1 = (y1 >= 0 && y1 < 64) ? 1.f : 0.f;
  const float vx0 = (x0 >= 0 && x0 < 64) ? 1.f : 0.f;
  const float vx1 = (x1 >= 0 && x1 < 64) ? 1.f : 0.f;
  DescOut o;
  o.y0c = min(max(y0, 0), 63); o.y1c = min(max(y1, 0), 63);
  o.x0c = min(max(x0, 0), 63); o.x1c = min(max(x1, 0), 63);
  o.w00 = (1.f - ly) * (1.f - lx) * vy0 * vx0;
  o.w01 = (1.f - ly) * lx * vy0 * vx1;
  o.w10 = ly * (1.f - lx) * vy1 * vx0;
  o.w11 = ly * lx * vy1 * vx1;
  return o;
}

// ---------------------------------------------------------------------------
// K2 fallback (R7 quad-descriptor form)
// ---------------------------------------------------------------------------
__global__ __launch_bounds__(256) void make_desc_k(
    const float* __restrict__ bof, float* __restrict__ ws) {
  const int d = blockIdx.x * 256 + threadIdx.x;
  DescOut q = desc_math(ws, bof, WS_OFFS, d);
  const int xf = min(q.x0c & ~1, 60);
  f4 g0 = {0.f, 0.f, 0.f, 0.f}, g1 = {0.f, 0.f, 0.f, 0.f};
#pragma unroll
  for (int j = 0; j < 4; ++j) {
    const int col = xf + j;
    g0[j] = (col == q.x0c ? q.w00 : 0.f) + (col == q.x1c ? q.w01 : 0.f);
    g1[j] = (col == q.x0c ? q.w10 : 0.f) + (col == q.x1c ? q.w11 : 0.f);
  }
  ((f4*)(ws + WS_GY0))[d] = g0;
  ((f4*)(ws + WS_GY1))[d] = g1;
  int2 ip; ip.x = (q.y0c << 6) + xf; ip.y = (q.y1c << 6) + xf;
  ((int2*)(ws + WS_IP))[d] = ip;
}

// ---------------------------------------------------------------------------
// K2 XT: half2-dup weights (uint4) + 4 corner positions (int4)
// ---------------------------------------------------------------------------
__global__ __launch_bounds__(256) void make_desc_xt(
    const float* __restrict__ bof, float* __restrict__ ws) {
  const int d = blockIdx.x * 256 + threadIdx.x;
  DescOut q = desc_math(ws, bof, OF2, d);
  uint4 wv;
  wv.x = duph(q.w00); wv.y = duph(q.w01);
  wv.z = duph(q.w10); wv.w = duph(q.w11);
  int4 pv;
  pv.x = (q.y0c << 6) + q.x0c;
  pv.y = (q.y0c << 6) + q.x1c;
  pv.z = (q.y1c << 6) + q.x0c;
  pv.w = (q.y1c << 6) + q.x1c;
  ((uint4*)(ws + DW2))[d] = wv;
  ((int4*)(ws + DP2))[d] = pv;
}

// ---------------------------------------------------------------------------
// K3 fallback: R7 gemm verbatim
// ---------------------------------------------------------------------------
__global__ __launch_bounds__(512, 4) void deform_gemm_k(
    const float* __restrict__ x, const float* __restrict__ ws,
    float* __restrict__ out) {
  __shared__ ushort Bsf[2][32][40];
  __shared__ f4   dG0[288];
  __shared__ f4   dG1[288];
  __shared__ int2 dIP[288];

  const int t     = threadIdx.x;
  const int bid   = blockIdx.x;
  const int xcd   = bid & 7;
  const int batch = xcd >> 1;
  const int j     = bid >> 3;
  const int sp0   = ((((xcd & 1) << 6) + j) << 5);
  const int nd0   = (batch << 12) + sp0;
  const int l     = t & 63;
  const int wv    = t >> 6;

  const int sn = t & 31;
  const int cs = t >> 5;
  const float* xb = x + ((long)batch << 20);
  const short* af = (const short*)(ws + WS_AFRAG);

  if (t < 288) {
    const int kk = t >> 5, s = t & 31;
    const int dg = (kk << 14) + nd0 + s;
    dG0[t] = ((const f4*)(ws + WS_GY0))[dg];
    dG1[t] = ((const f4*)(ws + WS_GY1))[dg];
    dIP[t] = ((const int2*)(ws + WS_IP))[dg];
  }
  __syncthreads();

  f4 acc[2][2];
#pragma unroll
  for (int i = 0; i < 2; ++i)
#pragma unroll
    for (int q = 0; q < 2; ++q) acc[i][q] = f4{0.f, 0.f, 0.f, 0.f};

  const int otb = wv << 1;
  b8 aA[2], aN[2];
  f4 g0, g1; int p0, p1;
  f4u r00, r01, r10, r11;

#define RDDESC(KK_) do { const int u_ = ((KK_) << 5) + sn;                   \
    g0 = dG0[u_]; g1 = dG1[u_];                                              \
    const int2 ip_ = dIP[u_]; p0 = ip_.x; p1 = ip_.y; } while (0)

#define GATHER(CG_) do {                                                     \
    const int c0_ = ((CG_) << 5) + (cs << 1);                                \
    const float* pl0_ = xb + ((long)c0_ << 12);                              \
    const float* pl1_ = pl0_ + 4096;                                         \
    r00 = *(const f4u*)(pl0_ + p0);  r01 = *(const f4u*)(pl0_ + p1);         \
    r10 = *(const f4u*)(pl1_ + p0);  r11 = *(const f4u*)(pl1_ + p1);         \
  } while (0)

#define COMBINE(BUF_) do {                                                   \
    const float v0_ = g0.x * r00.x + g0.y * r00.y + g0.z * r00.z +           \
                      g0.w * r00.w + g1.x * r01.x + g1.y * r01.y +           \
                      g1.z * r01.z + g1.w * r01.w;                           \
    const float v1_ = g0.x * r10.x + g0.y * r10.y + g0.z * r10.z +           \
                      g0.w * r10.w + g1.x * r11.x + g1.y * r11.y +           \
                      g1.z * r11.z + g1.w * r11.w;                           \
    ushort2 pk_; pk_.x = f2bf(v0_); pk_.y = f2bf(v1_);                       \
    *(ushort2*)&Bsf[BUF_][sn][cs << 1] = pk_; } while (0)

#define LOADA(I_, DST_) do {                                                 \
    _Pragma("unroll")                                                        \
    for (int m = 0; m < 2; ++m)                                              \
      DST_[m] = *(const b8*)(af + (((((I_) << 4) + otb + m) << 6) + l) * 8); \
  } while (0)

  RDDESC(0);
  GATHER(0);
  LOADA(0, aA);
  COMBINE(0);
  RDDESC(1);
  __syncthreads();

  int kkN = 1, cgN = 0;
  for (int i = 0; i < 72; ++i) {
    const int cur = i & 1;
    if (i < 71) {
      GATHER(cgN);
      LOADA(i + 1, aN);
    }
    b8 bB[2];
#pragma unroll
    for (int nt = 0; nt < 2; ++nt)
      bB[nt] = *(const b8*)&Bsf[cur][(nt << 4) + (l & 15)][(l >> 4) << 3];
#pragma unroll
    for (int mt = 0; mt < 2; ++mt)
#pragma unroll
      for (int nt = 0; nt < 2; ++nt)
        acc[mt][nt] = __builtin_amdgcn_mfma_f32_16x16x32_bf16(
            aA[mt], bB[nt], acc[mt][nt], 0, 0, 0);
    if (i < 71) {
      COMBINE(cur ^ 1);
      kkN++; if (kkN == 9) { kkN = 0; cgN++; }
      if (i < 70) RDDESC(kkN);
#pragma unroll
      for (int m = 0; m < 2; ++m) aA[m] = aN[m];
    }
    __syncthreads();
  }
#undef RDDESC
#undef GATHER
#undef COMBINE
#undef LOADA

  const float* bfold = ws + WS_BFOLD;
  const int q4 = (l >> 4) << 2;
  const int ow = wv << 5;
#pragma unroll
  for (int mt = 0; mt < 2; ++mt) {
    const int ob = ow + (mt << 4) + q4;
    const f4 bf = *(const f4*)&bfold[ob];
#pragma unroll
    for (int nt = 0; nt < 2; ++nt) {
      const int sp = sp0 + (nt << 4) + (l & 15);
#pragma unroll
      for (int r = 0; r < 4; ++r) {
        const int o = ob + r;
        out[(((batch << 8) + o) << 12) + sp] =
            fmaxf(acc[mt][nt][r] + bf[r], 0.f);
      }
    }
  }
}

// ---------------------------------------------------------------------------
// K3 big path: f16 MFMA GEMM, triple-buffered pipelined deformable im2col.
// Grid 256 x 512 thr (8 waves). Tile 256o x 64n; wave = 64o x 32n. BK=64:
// 36 iters (cw64-outer, kk-inner). STAGING LANE MAP (the R9 fix): within a
// wave, 16 samples x 4 contiguous 16B channel-slices -> the 4 slices of one
// sample share one 128B line => 16 lines per gather wave-instr (was 64).
// ---------------------------------------------------------------------------
__global__ __launch_bounds__(512, 2) void deform_gemm_f16(
    const float* __restrict__ ws, float* __restrict__ out) {
  __shared__ __align__(16) uint Bs[3][64][32];   // 24 KB f16 tiles
  __shared__ uint4 dW[576];                      // 9 KB
  __shared__ int4  dP[576];                      // 9 KB

  const int t     = threadIdx.x;
  const int bid   = blockIdx.x;
  const int xcd   = bid & 7;
  const int batch = xcd >> 1;
  const int half  = xcd & 1;
  const int slot  = bid >> 3;                    // 0..31
  const int sp0   = (half << 11) + (slot << 6);
  const int nd0   = (batch << 12) + sp0;
  const int l     = t & 63;
  const int wv    = t >> 6;                      // 0..7

  // staging ids: wave covers 16 samples x 4 contiguous slices (line-local)
  const int sn  = ((wv & 3) << 4) | (l & 15);    // sample column 0..63
  const int cg8 = ((wv >> 2) << 2) | (l >> 4);   // 8-ch slice 0..7
  const uint* xtu = (const uint*)(ws + XT2) + ((long)batch << 19);
  const _Float16* af = (const _Float16*)(ws + AF2);

  // fill descriptor LDS: 576 = 9 kk x 64 samples
  for (int u = t; u < 576; u += 512) {
    const int kk = u >> 6, s = u & 63;
    const int dg = (kk << 14) + nd0 + s;
    dW[u] = ((const uint4*)(ws + DW2))[dg];
    dP[u] = ((const int4*)(ws + DP2))[dg];
  }
  __syncthreads();

  f4 acc[4][2];
#pragma unroll
  for (int m = 0; m < 4; ++m)
#pragma unroll
    for (int nt = 0; nt < 2; ++nt) acc[m][nt] = f4{0.f, 0.f, 0.f, 0.f};

  uint4 cset0[4], cset1[4];           // two outstanding corner sets
  uint4 w0v, w1v, wq; int4 pq;
  h8 aA[4][2], aN[4][2];
  int kkd, kkg, cwg, bufc;

#define FRDD(W_, P_, KK_) do { const int u_ = ((KK_) << 6) + sn;             \
    W_ = dW[u_]; P_ = dP[u_]; } while (0)

#define FGATH(DST_, P_) do {                                                 \
    const int co_ = (cwg << 5) + (cg8 << 2);                                 \
    DST_[0] = *(const uint4*)(xtu + ((P_).x << 7) + co_);                    \
    DST_[1] = *(const uint4*)(xtu + ((P_).y << 7) + co_);                    \
    DST_[2] = *(const uint4*)(xtu + ((P_).z << 7) + co_);                    \
    DST_[3] = *(const uint4*)(xtu + ((P_).w << 7) + co_);                    \
  } while (0)

#define FCOMB(CS_, WV_, BUF_) do {                                           \
    const h2 wc0_ = u2h2((WV_).x), wc1_ = u2h2((WV_).y);                     \
    const h2 wc2_ = u2h2((WV_).z), wc3_ = u2h2((WV_).w);                     \
    uint4 r_;                                                                \
    r_.x = h22u(u2h2(CS_[0].x) * wc0_ + u2h2(CS_[1].x) * wc1_ +              \
                u2h2(CS_[2].x) * wc2_ + u2h2(CS_[3].x) * wc3_);              \
    r_.y = h22u(u2h2(CS_[0].y) * wc0_ + u2h2(CS_[1].y) * wc1_ +              \
                u2h2(CS_[2].y) * wc2_ + u2h2(CS_[3].y) * wc3_);              \
    r_.z = h22u(u2h2(CS_[0].z) * wc0_ + u2h2(CS_[1].z) * wc1_ +              \
                u2h2(CS_[2].z) * wc2_ + u2h2(CS_[3].z) * wc3_);              \
    r_.w = h22u(u2h2(CS_[0].w) * wc0_ + u2h2(CS_[1].w) * wc1_ +              \
                u2h2(CS_[2].w) * wc2_ + u2h2(CS_[3].w) * wc3_);              \
    *(uint4*)&Bs[BUF_][sn][(cg8 ^ (sn & 7)) << 2] = r_;                      \
  } while (0)

#define FLOADA(I_, DST_) do {                                                \
    _Pragma("unroll")                                                        \
    for (int m = 0; m < 4; ++m)                                              \
      _Pragma("unroll")                                                      \
      for (int s = 0; s < 2; ++s) {                                          \
        const int f_ = ((I_) << 1) + s;                                      \
        DST_[m][s] = *(const h8*)(af +                                       \
            ((((f_ << 4) + ((wv >> 1) << 2) + m) << 6) + l) * 8);            \
      }                                                                      \
  } while (0)

#define FMFMA(AC_, BUF_) do {                                                \
    h8 bB_[2][2];                                                            \
    _Pragma("unroll")                                                        \
    for (int nt = 0; nt < 2; ++nt)                                           \
      _Pragma("unroll")                                                      \
      for (int s = 0; s < 2; ++s) {                                          \
        const int snr_ = ((wv & 1) << 5) + (nt << 4) + (l & 15);             \
        const int ph_  = (((s << 2) + (l >> 4)) ^ (snr_ & 7)) << 2;          \
        bB_[nt][s] = *(const h8*)&Bs[BUF_][snr_][ph_];                       \
      }                                                                      \
    _Pragma("unroll")                                                        \
    for (int m = 0; m < 4; ++m)                                              \
      _Pragma("unroll")                                                      \
      for (int nt = 0; nt < 2; ++nt) {                                       \
        acc[m][nt] = __builtin_amdgcn_mfma_f32_16x16x32_f16(                 \
            AC_[m][0], bB_[nt][0], acc[m][nt], 0, 0, 0);                     \
        acc[m][nt] = __builtin_amdgcn_mfma_f32_16x16x32_f16(                 \
            AC_[m][1], bB_[nt][1], acc[m][nt], 0, 0, 0);                     \
      }                                                                      \
  } while (0)

#define FBODY(I_, AC_, AN_, CC_, WC_, CN_, WN_) do {                         \
    if ((I_) < 34) {                                                         \
      WN_ = wq; FGATH(CN_, pq);                                              \
      kkg++; if (kkg == 9) { kkg = 0; cwg++; }                               \
    }                                                                        \
    if ((I_) < 33) { FRDD(wq, pq, kkd); kkd = (kkd == 8) ? 0 : kkd + 1; }    \
    const int bufn_ = (bufc == 2) ? 0 : bufc + 1;                            \
    FMFMA(AC_, bufc);                                                        \
    if ((I_) < 35) {                                                         \
      FLOADA((I_) + 1, AN_);                                                 \
      FCOMB(CC_, WC_, bufn_);                                                \
    }                                                                        \
    bufc = bufn_;                                                            \
    __syncthreads();                                                         \
  } while (0)

  // ---- prologue: gather iters 0 and 1 (cw=0), desc queue = iter 2 ----
  {
    uint4 wA; int4 pA;
    cwg = 0;
    FRDD(wA, pA, 0);
    FGATH(cset0, pA);
    FRDD(w1v, pA, 1);
    FGATH(cset1, pA);
    FRDD(wq, pq, 2);
    FLOADA(0, aA);
    FCOMB(cset0, wA, 0);
    kkd = 3; kkg = 2; bufc = 0;
  }
  __syncthreads();

  for (int i = 0; i < 36; i += 2) {
    FBODY(i,     aA, aN, cset1, w1v, cset0, w0v);
    FBODY(i + 1, aN, aA, cset0, w0v, cset1, w1v);
  }

  const float* bfold = ws + BF2;
  const int quad = l >> 4;
  const int ow = (wv >> 1) << 6;
  const int nw = (wv & 1) << 5;
#pragma unroll
  for (int m = 0; m < 4; ++m) {
    const int ob = ow + (m << 4) + (quad << 2);
    const f4 bf = *(const f4*)&bfold[ob];
#pragma unroll
    for (int nt = 0; nt < 2; ++nt) {
      const int sp = sp0 + nw + (nt << 4) + (l & 15);
#pragma unroll
      for (int r = 0; r < 4; ++r) {
        out[(((batch << 8) + ob + r) << 12) + sp] =
            fmaxf(acc[m][nt][r] + bf[r], 0.f);
      }
    }
  }
}

// ---------------------------------------------------------------------------
extern "C" void kernel_launch(void* const* d_in, const int* in_sizes, int n_in,
                              void* d_out, int out_size, void* d_ws, size_t ws_size,
                              hipStream_t stream) {
  const float* x     = (const float*)d_in[0];
  const float* wof   = (const float*)d_in[1];
  const float* bof   = (const float*)d_in[2];
  const float* w     = (const float*)d_in[3];
  const float* bias  = (const float*)d_in[4];
  const float* gamma = (const float*)d_in[5];
  const float* beta  = (const float*)d_in[6];
  const float* mean  = (const float*)d_in[7];
  const float* var   = (const float*)d_in[8];
  float* out = (float*)d_out;
  float* ws  = (float*)d_ws;

  const bool big = ws_size >= (size_t)XT_TOTAL_BYTES;
  if (big) {
    hipLaunchKernelGGL(prep_k, dim3(288), dim3(256), 0, stream,
                       w, wof, bias, gamma, beta, mean, var, ws,
                       AF2, BF2, WH2, WL2, 1);
    hipLaunchKernelGGL(transpose_k, dim3(2048), dim3(256), 0, stream, x, ws);
    hipLaunchKernelGGL(offset_part_k, dim3(1024), dim3(256), 0, stream, x, ws);
    hipLaunchKernelGGL(make_desc_xt, dim3(576), dim3(256), 0, stream, bof, ws);
    hipLaunchKernelGGL(deform_gemm_f16, dim3(256), dim3(512), 0, stream,
                       ws, out);
  } else {
    hipLaunchKernelGGL(prep_k, dim3(288), dim3(256), 0, stream,
                       w, wof, bias, gamma, beta, mean, var, ws,
                       WS_AFRAG, WS_BFOLD, WS_K1WH, WS_K1WL, 0);
    hipLaunchKernelGGL(offset_mfma_k, dim3(256), dim3(256), 0, stream,
                       x, ws, WS_OFFS, WS_K1WH, WS_K1WL);
    hipLaunchKernelGGL(make_desc_k, dim3(576), dim3(256), 0, stream, bof, ws);
    hipLaunchKernelGGL(deform_gemm_k, dim3(512), dim3(512), 0, stream,
                       x, ws, out);
  }
}